// Round 1
// baseline (3388.384 us; speedup 1.0000x reference)
//
#include <hip/hip_runtime.h>

// Problem constants (fixed by setup_inputs)
#define B_  2
#define CK_ 64
#define CV_ 512
#define H_  48
#define W_  48
#define M_  18432   // T*H*W
#define N_  2304    // H*W

typedef __bf16 bf16x8 __attribute__((ext_vector_type(8)));
typedef float  f32x4  __attribute__((ext_vector_type(4)));

// log2(e)/8 and 2*log2(e)/8 — softmax logits are (2*ab - |k|^2)/sqrt(64), computed in exp2 domain
#define C_AB  0.36067376f
#define C_KSQ 0.18033688f

__device__ inline f32x4 mfma16(bf16x8 a, bf16x8 b, f32x4 c) {
    return __builtin_amdgcn_mfma_f32_16x16x32_bf16(a, b, c, 0, 0, 0);
}

// ---------------------------------------------------------------------------
// Kernel 1: ksq_s[b][m] = sum_k mk[b][k][m]^2 * (log2e/8)   (pre-scaled)
// ---------------------------------------------------------------------------
__global__ __launch_bounds__(256) void ksq_kernel(const float* __restrict__ mk,
                                                  float* __restrict__ ksq_s) {
    const int idx = blockIdx.x * 256 + threadIdx.x;   // grid sized exactly B*M/256
    const int b = idx / M_, m = idx % M_;
    const float* p = mk + (size_t)b * CK_ * M_ + m;
    float s = 0.f;
#pragma unroll
    for (int k = 0; k < CK_; ++k) {
        float v = p[(size_t)k * M_];
        s += v * v;
    }
    ksq_s[idx] = s * C_KSQ;
}

// ---------------------------------------------------------------------------
// Kernel 2: softmax denominators. inv_ws[b][n] = 1 / sum_m exp(logit(m,n)).
// No max-subtraction needed: logits <= ~12, exp2 args bounded, fp32 sum safe.
// Block: 256 thr = 4 waves; block covers 32 queries (2 n-subtiles), waves
// split the M axis 4 ways; partials merged in LDS.
// ---------------------------------------------------------------------------
__global__ __launch_bounds__(256) void stats_kernel(const float* __restrict__ mk,
                                                    const float* __restrict__ qk,
                                                    const float* __restrict__ ksq_s,
                                                    float* __restrict__ inv_ws) {
    const int nt = blockIdx.x;           // 0..71
    const int b  = blockIdx.y;
    const int tid  = threadIdx.x;
    const int w    = tid >> 6, lane = tid & 63;
    const int g    = lane >> 4, nl = lane & 15;
    const int n0   = nt * 32;

    const float* qkb = qk + (size_t)b * CK_ * N_;
    const float* mkb = mk + (size_t)b * CK_ * M_;
    const float* ksb = ksq_s + (size_t)b * M_;

    // Q B-frags: col = nl, k = 32*ks + 8*g + i
    bf16x8 qf[2][2];
#pragma unroll
    for (int sub = 0; sub < 2; ++sub)
#pragma unroll
      for (int ks = 0; ks < 2; ++ks)
#pragma unroll
        for (int i = 0; i < 8; ++i)
            qf[sub][ks][i] = (__bf16)qkb[(size_t)(32*ks + 8*g + i) * N_ + (n0 + 16*sub + nl)];

    float part0 = 0.f, part1 = 0.f;

    for (int it = 0; it < M_ / 64; ++it) {            // 288 iters, wave w owns m-tile 4*it+w
        const int m0 = (it * 4 + w) * 16;
        bf16x8 af[2];                                  // K A-frags: row = nl (m), k = 32*ks+8g+i
#pragma unroll
        for (int ks = 0; ks < 2; ++ks)
#pragma unroll
          for (int i = 0; i < 8; ++i)
            af[ks][i] = (__bf16)mkb[(size_t)(32*ks + 8*g + i) * M_ + (m0 + nl)];
        float kq[4];
#pragma unroll
        for (int rr = 0; rr < 4; ++rr) kq[rr] = ksb[m0 + 4*g + rr];

        f32x4 d0 = {0.f,0.f,0.f,0.f}, d1 = {0.f,0.f,0.f,0.f};
        d0 = mfma16(af[0], qf[0][0], d0);  d0 = mfma16(af[1], qf[0][1], d0);
        d1 = mfma16(af[0], qf[1][0], d1);  d1 = mfma16(af[1], qf[1][1], d1);
#pragma unroll
        for (int rr = 0; rr < 4; ++rr) {
            part0 += exp2f(d0[rr] * C_AB - kq[rr]);
            part1 += exp2f(d1[rr] * C_AB - kq[rr]);
        }
    }
    // reduce the 4 m-row groups (C rows live across lane>>4)
    part0 += __shfl_xor(part0, 16);  part0 += __shfl_xor(part0, 32);
    part1 += __shfl_xor(part1, 16);  part1 += __shfl_xor(part1, 32);

    __shared__ float lds[4][32];
    if (lane < 16) { lds[w][nl] = part0; lds[w][16 + nl] = part1; }
    __syncthreads();
    if (tid < 32) {
        float tot = lds[0][tid] + lds[1][tid] + lds[2][tid] + lds[3][tid];
        inv_ws[(size_t)b * N_ + n0 + tid] = 1.0f / tot;
    }
}

// ---------------------------------------------------------------------------
// Kernel 3: PV. Block = 128 thr = 2 waves; wave owns a 16-query subtile and
// a 128-channel CV quarter (blockIdx.y). Recomputes QK^T (cheap, K=64),
// p = exp2(...) * inv[n], redistributes P via per-wave LDS (C-layout ->
// B-frag layout), accumulates O[c][n] with V^T as the MFMA A operand so the
// output store is coalesced along n.
// ---------------------------------------------------------------------------
__global__ __launch_bounds__(128) void pv_kernel(const float* __restrict__ mk,
                                                 const float* __restrict__ qk,
                                                 const float* __restrict__ mv,
                                                 const float* __restrict__ ksq_s,
                                                 const float* __restrict__ inv_ws,
                                                 float* __restrict__ out) {
    const int nt = blockIdx.x;   // 0..71
    const int cq = blockIdx.y;   // 0..3
    const int b  = blockIdx.z;   // 0..1
    const int tid  = threadIdx.x;
    const int w    = tid >> 6, lane = tid & 63;
    const int g    = lane >> 4, nl = lane & 15;
    const int nb   = nt * 32 + w * 16;
    const int cb   = cq * 128;

    const float* qkb = qk + (size_t)b * CK_ * N_;
    const float* mkb = mk + (size_t)b * CK_ * M_;
    const float* mvb = mv + (size_t)b * CV_ * M_;
    const float* ksb = ksq_s + (size_t)b * M_;
    const float inv_l = inv_ws[(size_t)b * N_ + nb + nl];

    // per-wave P tile [16 n][32 m], row stride 40 (80B) to spread banks; 16B-aligned b128 reads
    __shared__ __align__(16) __bf16 plds[2][16][40];
    __bf16 (*pl)[40] = plds[w];

    bf16x8 qf[2];
#pragma unroll
    for (int ks = 0; ks < 2; ++ks)
#pragma unroll
      for (int i = 0; i < 8; ++i)
        qf[ks][i] = (__bf16)qkb[(size_t)(32*ks + 8*g + i) * N_ + (nb + nl)];

    f32x4 acc[8];
#pragma unroll
    for (int ct = 0; ct < 8; ++ct) acc[ct] = (f32x4){0.f,0.f,0.f,0.f};

    for (int ms = 0; ms < M_ / 32; ++ms) {            // 576 iters
        const int m0 = ms * 32;
        // --- QK^T for the 32-m strip, p -> LDS ---
#pragma unroll
        for (int mt = 0; mt < 2; ++mt) {
            bf16x8 af[2];
#pragma unroll
            for (int ks = 0; ks < 2; ++ks)
#pragma unroll
              for (int i = 0; i < 8; ++i)
                af[ks][i] = (__bf16)mkb[(size_t)(32*ks + 8*g + i) * M_ + (m0 + 16*mt + nl)];
            f32x4 d = {0.f,0.f,0.f,0.f};
            d = mfma16(af[0], qf[0], d);
            d = mfma16(af[1], qf[1], d);
#pragma unroll
            for (int rr = 0; rr < 4; ++rr) {
                const float kq = ksb[m0 + 16*mt + 4*g + rr];
                const float p  = exp2f(d[rr] * C_AB - kq) * inv_l;
                pl[nl][16*mt + 4*g + rr] = (__bf16)p;   // C-layout: n=nl, m=16mt+4g+rr
            }
        }
        // --- P B-frag: col n = nl, k(m) = 8g+i, contiguous 16B ---
        const bf16x8 pb = *(const bf16x8*)&pl[nl][8 * g];
        // --- V^T A-frags (row c = nl, k(m) = 8g+i -> 8 contiguous floats) + MFMA ---
#pragma unroll
        for (int ct = 0; ct < 8; ++ct) {
            const float* vp = mvb + (size_t)(cb + 16*ct + nl) * M_ + (m0 + 8*g);
            const float4 v0 = *(const float4*)vp;
            const float4 v1 = *(const float4*)(vp + 4);
            bf16x8 va;
            va[0]=(__bf16)v0.x; va[1]=(__bf16)v0.y; va[2]=(__bf16)v0.z; va[3]=(__bf16)v0.w;
            va[4]=(__bf16)v1.x; va[5]=(__bf16)v1.y; va[6]=(__bf16)v1.z; va[7]=(__bf16)v1.w;
            acc[ct] = mfma16(va, pb, acc[ct]);
        }
    }

    // store mem (unscaled) into out channels [cb..cb+128); row=c, col=n -> coalesced along n
    float* ob = out + (size_t)b * (2 * CV_) * N_;
#pragma unroll
    for (int ct = 0; ct < 8; ++ct)
#pragma unroll
      for (int rr = 0; rr < 4; ++rr)
        ob[(size_t)(cb + 16*ct + 4*g + rr) * N_ + (nb + nl)] = acc[ct][rr];
}

// ---------------------------------------------------------------------------
// Kernel 4: gate[b][p] = sigmoid(conv3x3([mem(out), qv, mask]) + bias).
// One block per output pixel; threads split the 1025 channels; block reduce.
// ---------------------------------------------------------------------------
__global__ __launch_bounds__(256) void conv_gate_kernel(const float* __restrict__ out_mem,
                                                        const float* __restrict__ qv,
                                                        const float* __restrict__ mask,
                                                        const float* __restrict__ cw,
                                                        const float* __restrict__ cbias,
                                                        float* __restrict__ gate_ws) {
    const int p = blockIdx.x;            // 0..N-1
    const int b = blockIdx.y;
    const int y = p / W_, x = p % W_;
    const int tid = threadIdx.x;

    float partial = 0.f;
    for (int c = tid; c < 2 * CV_ + 1; c += 256) {
        const float* src;
        if (c < CV_)          src = out_mem + ((size_t)b * (2*CV_) + c) * N_;
        else if (c < 2 * CV_) src = qv + ((size_t)b * CV_ + (c - CV_)) * N_;
        else                  src = mask + (size_t)b * N_;
        const float* wr = cw + c * 9;
#pragma unroll
        for (int dy = -1; dy <= 1; ++dy) {
            const int yy = y + dy;
            if (yy < 0 || yy >= H_) continue;
#pragma unroll
            for (int dx = -1; dx <= 1; ++dx) {
                const int xx = x + dx;
                if (xx < 0 || xx >= W_) continue;
                partial += src[yy * W_ + xx] * wr[(dy+1)*3 + (dx+1)];
            }
        }
    }
    partial += __shfl_xor(partial, 1);  partial += __shfl_xor(partial, 2);
    partial += __shfl_xor(partial, 4);  partial += __shfl_xor(partial, 8);
    partial += __shfl_xor(partial, 16); partial += __shfl_xor(partial, 32);
    __shared__ float red[4];
    if ((tid & 63) == 0) red[tid >> 6] = partial;
    __syncthreads();
    if (tid == 0) {
        const float s = red[0] + red[1] + red[2] + red[3] + cbias[0];
        gate_ws[(size_t)b * N_ + p] = 1.f / (1.f + exp2f(-s * 1.44269504f));
    }
}

// ---------------------------------------------------------------------------
// Kernel 5: out[b][ch][n] = (ch<512 ? mem : qv) * gate[b][n]
// ---------------------------------------------------------------------------
__global__ __launch_bounds__(256) void finalize_kernel(const float* __restrict__ qv,
                                                       const float* __restrict__ gate_ws,
                                                       float* __restrict__ out) {
    const int idx = blockIdx.x * 256 + threadIdx.x;   // float4 index, grid sized exactly
    const int n4 = N_ / 4;                            // 576
    const int pos4 = idx % n4;
    const int row  = idx / n4;                        // b*1024 + ch
    const int b = row >> 10, ch = row & 1023;

    const float4 gv = *(const float4*)(gate_ws + (size_t)b * N_ + pos4 * 4);
    float* op = out + (size_t)row * N_ + pos4 * 4;
    float4 v;
    if (ch < CV_) v = *(const float4*)op;
    else          v = *(const float4*)(qv + ((size_t)b * CV_ + (ch - CV_)) * N_ + pos4 * 4);
    v.x *= gv.x; v.y *= gv.y; v.z *= gv.z; v.w *= gv.w;
    *(float4*)op = v;
}

// ---------------------------------------------------------------------------
extern "C" void kernel_launch(void* const* d_in, const int* in_sizes, int n_in,
                              void* d_out, int out_size, void* d_ws, size_t ws_size,
                              hipStream_t stream) {
    (void)in_sizes; (void)n_in; (void)out_size; (void)ws_size;
    const float* mk    = (const float*)d_in[0];
    const float* qk    = (const float*)d_in[1];
    const float* mv    = (const float*)d_in[2];
    const float* qv    = (const float*)d_in[3];
    const float* mask  = (const float*)d_in[4];
    const float* cw    = (const float*)d_in[5];
    const float* cbias = (const float*)d_in[6];
    float* outf = (float*)d_out;

    // small scratch: [B*M] scaled ksq | [B*N] inv denom | [B*N] gate  = 184 KB
    float* ksq_s   = (float*)d_ws;
    float* inv_ws  = ksq_s + (size_t)B_ * M_;
    float* gate_ws = inv_ws + (size_t)B_ * N_;

    ksq_kernel   <<<dim3(B_ * M_ / 256), 256, 0, stream>>>(mk, ksq_s);
    stats_kernel <<<dim3(N_ / 32, B_),   256, 0, stream>>>(mk, qk, ksq_s, inv_ws);
    pv_kernel    <<<dim3(N_ / 32, 4, B_), 128, 0, stream>>>(mk, qk, mv, ksq_s, inv_ws, outf);
    conv_gate_kernel<<<dim3(N_, B_), 256, 0, stream>>>(outf, qv, mask, cw, cbias, gate_ws);
    finalize_kernel <<<dim3((B_ * 2 * CV_ * N_ / 4) / 256), 256, 0, stream>>>(qv, gate_ws, outf);
}

// Round 2
// 691.920 us; speedup vs baseline: 4.8971x; 4.8971x over previous
//
#include <hip/hip_runtime.h>

// Problem constants (fixed by setup_inputs)
#define B_  2
#define CK_ 64
#define CV_ 512
#define H_  48
#define W_  48
#define M_  18432   // T*H*W
#define N_  2304    // H*W

#define SSPLIT 4
#define MSEG   (M_ / SSPLIT)   // 4608
#define NSTRIPS (MSEG / 32)    // 144

typedef __bf16 bf16x8 __attribute__((ext_vector_type(8)));
typedef __bf16 bf16x4 __attribute__((ext_vector_type(4)));
typedef float  f32x4  __attribute__((ext_vector_type(4)));

// exp2-domain constants: logit = (2*ab - |k|^2)/sqrt(64); exp(l) = 2^(ab*C_AB - ksq*C_KSQ)
#define C_AB  0.36067376f
#define C_KSQ 0.18033688f

__device__ inline f32x4 mfma16(bf16x8 a, bf16x8 b, f32x4 c) {
    return __builtin_amdgcn_mfma_f32_16x16x32_bf16(a, b, c, 0, 0, 0);
}

// ===========================================================================
// Main path (needs ~80.5 MB workspace)
// ===========================================================================

// prep_k: kbf[b][m][k] = bf16(mk[b][k][m])  (m-major transpose, coalesced reads
// across threads), plus ksq_s[b][m] = sum_k mk^2 * C_KSQ.
__global__ __launch_bounds__(256) void prep_k(const float* __restrict__ mk,
                                              __bf16* __restrict__ kbf,
                                              float* __restrict__ ksq_s) {
    const int idx = blockIdx.x * 256 + threadIdx.x;   // B*M threads
    const int b = idx / M_, m = idx % M_;
    const float* src = mk + (size_t)b * CK_ * M_ + m;
    __bf16* dst = kbf + (size_t)idx * 64;
    float s = 0.f;
#pragma unroll
    for (int c = 0; c < 8; ++c) {
        bf16x8 o;
#pragma unroll
        for (int j = 0; j < 8; ++j) {
            float v = src[(size_t)(8 * c + j) * M_];
            s += v * v;
            o[j] = (__bf16)v;
        }
        *(bf16x8*)(dst + 8 * c) = o;
    }
    ksq_s[idx] = s * C_KSQ;
}

// prep_v: straight f32 -> bf16 stream, same [b][c][m] layout.
__global__ __launch_bounds__(256) void prep_v(const float* __restrict__ mv,
                                              __bf16* __restrict__ vbf) {
    const int idx = blockIdx.x * 256 + threadIdx.x;   // B*CV*M/8 threads
    const float4* s4 = (const float4*)mv + (size_t)idx * 2;
    const float4 a = s4[0], c = s4[1];
    bf16x8 o;
    o[0]=(__bf16)a.x; o[1]=(__bf16)a.y; o[2]=(__bf16)a.z; o[3]=(__bf16)a.w;
    o[4]=(__bf16)c.x; o[5]=(__bf16)c.y; o[6]=(__bf16)c.z; o[7]=(__bf16)c.w;
    ((bf16x8*)vbf)[idx] = o;
}

// flash: one block = 32 queries x all 512 channels x 1/4 of the memory axis.
// Single-pass: unnormalized O + denominator accumulated together (logits are
// bounded, no running max needed). 4 waves: wave w owns channels [128w,128w+128)
// for PV and the QK assignment (nsub=w&1, msub=w>>1).
__global__ __launch_bounds__(256, 3) void flash_kernel(const __bf16* __restrict__ kbf,
                                                       const float* __restrict__ qk,
                                                       const __bf16* __restrict__ vbf,
                                                       const float* __restrict__ ksq_s,
                                                       float* __restrict__ partO,
                                                       float* __restrict__ partD) {
    // XCD-chunked swizzle: all 72 n-tiles of one (s,b) land on one XCD so their
    // identical V sweep hits L2. (Heuristic only — correctness-neutral.)
    const int id = blockIdx.x;                 // 0..575
    const int work = (id & 7) * 72 + (id >> 3);
    const int nt = work % 72;
    const int sb = work / 72;
    const int s  = sb & 3, b = sb >> 2;

    const int tid = threadIdx.x;
    const int w = tid >> 6, lane = tid & 63, g = lane >> 4, nl = lane & 15;
    const int nsub_w = w & 1, msub_w = w >> 1;
    const int n0 = nt * 32;
    const int cw = 128 * w;
    const int m_base = s * MSEG;

    __shared__ __align__(16) __bf16 Kl[32][72];   // [m][k], pad 72 -> 2-way banks
    __shared__ __align__(16) __bf16 Pl[32][40];   // [n][m], pad 40 -> 2-way banks
    __shared__ float ksql[32];
    __shared__ float dred[4][16];

    // Q B-frag for this wave's nsub (16 scalar f32 loads, once per block)
    const float* qkb = qk + (size_t)b * CK_ * N_;
    const int nq = n0 + 16 * nsub_w + nl;
    bf16x8 qf0, qf1;
#pragma unroll
    for (int i = 0; i < 8; ++i) {
        qf0[i] = (__bf16)qkb[(size_t)(8 * g + i) * N_ + nq];
        qf1[i] = (__bf16)qkb[(size_t)(32 + 8 * g + i) * N_ + nq];
    }

    const __bf16* kb  = kbf + (size_t)b * M_ * 64;
    const __bf16* vb  = vbf + (size_t)b * CV_ * M_;
    const float*  ksb = ksq_s + (size_t)b * M_ + m_base;

    f32x4 acc[8][2];
#pragma unroll
    for (int ct = 0; ct < 8; ++ct) { acc[ct][0] = (f32x4){0,0,0,0}; acc[ct][1] = (f32x4){0,0,0,0}; }
    float denom = 0.f;

    for (int ms = 0; ms < NSTRIPS; ++ms) {
        const int m0 = m_base + ms * 32;

        // --- issue V fragment loads early (global bf16, no LDS) ---
        bf16x8 va[8];
#pragma unroll
        for (int ct = 0; ct < 8; ++ct)
            va[ct] = *(const bf16x8*)(vb + (size_t)(cw + 16 * ct + nl) * M_ + m0 + 8 * g);

        // --- stage K strip (threads 0..127) + ksq (128..159) ---
        if (tid < 128) {
            const int j = tid >> 2, q = tid & 3;            // row m0+j, 16-elem quarter q
            const __bf16* src = kb + (size_t)(m0 + j) * 64 + 16 * q;
            bf16x8 k0 = *(const bf16x8*)src;
            bf16x8 k1 = *(const bf16x8*)(src + 8);
            *(bf16x8*)&Kl[j][16 * q]     = k0;
            *(bf16x8*)&Kl[j][16 * q + 8] = k1;
        } else if (tid < 160) {
            ksql[tid - 128] = ksb[ms * 32 + (tid - 128)];
        }
        __syncthreads();

        // --- QK^T (wave's (nsub,msub) 16x16 tile) -> p -> Pl ---
        {
            bf16x8 af0 = *(const bf16x8*)&Kl[16 * msub_w + nl][8 * g];
            bf16x8 af1 = *(const bf16x8*)&Kl[16 * msub_w + nl][32 + 8 * g];
            f32x4 d = {0,0,0,0};
            d = mfma16(af0, qf0, d);
            d = mfma16(af1, qf1, d);
            bf16x4 pw;
#pragma unroll
            for (int rr = 0; rr < 4; ++rr) {
                const float p = __builtin_amdgcn_exp2f(d[rr] * C_AB - ksql[16 * msub_w + 4 * g + rr]);
                denom += p;
                pw[rr] = (__bf16)p;
            }
            *(bf16x4*)&Pl[16 * nsub_w + nl][16 * msub_w + 4 * g] = pw;
        }
        __syncthreads();

        // --- PV: all 4 waves, 16 MFMA each ---
        const bf16x8 pb0 = *(const bf16x8*)&Pl[nl][8 * g];
        const bf16x8 pb1 = *(const bf16x8*)&Pl[16 + nl][8 * g];
#pragma unroll
        for (int ct = 0; ct < 8; ++ct) {
            acc[ct][0] = mfma16(va[ct], pb0, acc[ct][0]);
            acc[ct][1] = mfma16(va[ct], pb1, acc[ct][1]);
        }
        // next iteration's stage/P-write is fenced by the barrier at loop top (A)
    }

    // --- denominator: reduce over g (m-rows) then across msub wave pairs ---
    denom += __shfl_xor(denom, 16);
    denom += __shfl_xor(denom, 32);
    if (lane < 16) dred[w][nl] = denom;
    __syncthreads();
    if (w < 2 && lane < 16)
        partD[(size_t)(s * B_ + b) * N_ + n0 + 16 * w + nl] = dred[w][nl] + dred[w + 2][nl];

    // --- unnormalized partial O ---
    float* po = partO + ((size_t)(s * B_ + b) * CV_) * N_;
#pragma unroll
    for (int ct = 0; ct < 8; ++ct)
#pragma unroll
      for (int ns = 0; ns < 2; ++ns)
#pragma unroll
        for (int rr = 0; rr < 4; ++rr)
            po[(size_t)(cw + 16 * ct + 4 * g + rr) * N_ + (n0 + 16 * ns + nl)] = acc[ct][ns][rr];
}

// reduce: mem[b][c][n] = sum_s partO / sum_s partD  -> d_out channels 0..511
__global__ __launch_bounds__(256) void reduce_kernel(const float* __restrict__ partO,
                                                     const float* __restrict__ partD,
                                                     float* __restrict__ out) {
    const int idx = blockIdx.x * 256 + threadIdx.x;   // B*CV*(N/4) threads
    const int n4 = idx % (N_ / 4);
    const int c  = (idx / (N_ / 4)) % CV_;
    const int b  = idx / ((N_ / 4) * CV_);
    float4 dsum = {0,0,0,0}, osum = {0,0,0,0};
#pragma unroll
    for (int s = 0; s < SSPLIT; ++s) {
        const float4 dv = *(const float4*)(partD + (size_t)(s * B_ + b) * N_ + n4 * 4);
        const float4 ov = *(const float4*)(partO + ((size_t)(s * B_ + b) * CV_ + c) * N_ + n4 * 4);
        dsum.x += dv.x; dsum.y += dv.y; dsum.z += dv.z; dsum.w += dv.w;
        osum.x += ov.x; osum.y += ov.y; osum.z += ov.z; osum.w += ov.w;
    }
    float4 r;
    r.x = osum.x / dsum.x; r.y = osum.y / dsum.y; r.z = osum.z / dsum.z; r.w = osum.w / dsum.w;
    *(float4*)(out + ((size_t)b * (2 * CV_) + c) * N_ + n4 * 4) = r;
}

// ===========================================================================
// Fallback path (round-1 kernels, verified; used when ws_size is too small)
// ===========================================================================

__global__ __launch_bounds__(256) void ksq_kernel(const float* __restrict__ mk,
                                                  float* __restrict__ ksq_s) {
    const int idx = blockIdx.x * 256 + threadIdx.x;
    const int b = idx / M_, m = idx % M_;
    const float* p = mk + (size_t)b * CK_ * M_ + m;
    float s = 0.f;
#pragma unroll
    for (int k = 0; k < CK_; ++k) { float v = p[(size_t)k * M_]; s += v * v; }
    ksq_s[idx] = s * C_KSQ;
}

__global__ __launch_bounds__(256) void stats_kernel(const float* __restrict__ mk,
                                                    const float* __restrict__ qk,
                                                    const float* __restrict__ ksq_s,
                                                    float* __restrict__ inv_ws) {
    const int nt = blockIdx.x;
    const int b  = blockIdx.y;
    const int tid  = threadIdx.x;
    const int w    = tid >> 6, lane = tid & 63;
    const int g    = lane >> 4, nl = lane & 15;
    const int n0   = nt * 32;
    const float* qkb = qk + (size_t)b * CK_ * N_;
    const float* mkb = mk + (size_t)b * CK_ * M_;
    const float* ksb = ksq_s + (size_t)b * M_;
    bf16x8 qf[2][2];
#pragma unroll
    for (int sub = 0; sub < 2; ++sub)
#pragma unroll
      for (int ks = 0; ks < 2; ++ks)
#pragma unroll
        for (int i = 0; i < 8; ++i)
            qf[sub][ks][i] = (__bf16)qkb[(size_t)(32*ks + 8*g + i) * N_ + (n0 + 16*sub + nl)];
    float part0 = 0.f, part1 = 0.f;
    for (int it = 0; it < M_ / 64; ++it) {
        const int m0 = (it * 4 + w) * 16;
        bf16x8 af[2];
#pragma unroll
        for (int ks = 0; ks < 2; ++ks)
#pragma unroll
          for (int i = 0; i < 8; ++i)
            af[ks][i] = (__bf16)mkb[(size_t)(32*ks + 8*g + i) * M_ + (m0 + nl)];
        float kq[4];
#pragma unroll
        for (int rr = 0; rr < 4; ++rr) kq[rr] = ksb[m0 + 4*g + rr];
        f32x4 d0 = {0.f,0.f,0.f,0.f}, d1 = {0.f,0.f,0.f,0.f};
        d0 = mfma16(af[0], qf[0][0], d0);  d0 = mfma16(af[1], qf[0][1], d0);
        d1 = mfma16(af[0], qf[1][0], d1);  d1 = mfma16(af[1], qf[1][1], d1);
#pragma unroll
        for (int rr = 0; rr < 4; ++rr) {
            part0 += exp2f(d0[rr] * C_AB - kq[rr]);
            part1 += exp2f(d1[rr] * C_AB - kq[rr]);
        }
    }
    part0 += __shfl_xor(part0, 16);  part0 += __shfl_xor(part0, 32);
    part1 += __shfl_xor(part1, 16);  part1 += __shfl_xor(part1, 32);
    __shared__ float lds[4][32];
    if (lane < 16) { lds[w][nl] = part0; lds[w][16 + nl] = part1; }
    __syncthreads();
    if (tid < 32) {
        float tot = lds[0][tid] + lds[1][tid] + lds[2][tid] + lds[3][tid];
        inv_ws[(size_t)b * N_ + n0 + tid] = 1.0f / tot;
    }
}

__global__ __launch_bounds__(128) void pv_kernel(const float* __restrict__ mk,
                                                 const float* __restrict__ qk,
                                                 const float* __restrict__ mv,
                                                 const float* __restrict__ ksq_s,
                                                 const float* __restrict__ inv_ws,
                                                 float* __restrict__ out) {
    const int nt = blockIdx.x, cq = blockIdx.y, b = blockIdx.z;
    const int tid  = threadIdx.x;
    const int w    = tid >> 6, lane = tid & 63;
    const int g    = lane >> 4, nl = lane & 15;
    const int nb   = nt * 32 + w * 16;
    const int cb   = cq * 128;
    const float* qkb = qk + (size_t)b * CK_ * N_;
    const float* mkb = mk + (size_t)b * CK_ * M_;
    const float* mvb = mv + (size_t)b * CV_ * M_;
    const float* ksb = ksq_s + (size_t)b * M_;
    const float inv_l = inv_ws[(size_t)b * N_ + nb + nl];
    __shared__ __align__(16) __bf16 plds[2][16][40];
    __bf16 (*pl)[40] = plds[w];
    bf16x8 qf[2];
#pragma unroll
    for (int ks = 0; ks < 2; ++ks)
#pragma unroll
      for (int i = 0; i < 8; ++i)
        qf[ks][i] = (__bf16)qkb[(size_t)(32*ks + 8*g + i) * N_ + (nb + nl)];
    f32x4 acc[8];
#pragma unroll
    for (int ct = 0; ct < 8; ++ct) acc[ct] = (f32x4){0.f,0.f,0.f,0.f};
    for (int ms = 0; ms < M_ / 32; ++ms) {
        const int m0 = ms * 32;
#pragma unroll
        for (int mt = 0; mt < 2; ++mt) {
            bf16x8 af[2];
#pragma unroll
            for (int ks = 0; ks < 2; ++ks)
#pragma unroll
              for (int i = 0; i < 8; ++i)
                af[ks][i] = (__bf16)mkb[(size_t)(32*ks + 8*g + i) * M_ + (m0 + 16*mt + nl)];
            f32x4 d = {0.f,0.f,0.f,0.f};
            d = mfma16(af[0], qf[0], d);
            d = mfma16(af[1], qf[1], d);
#pragma unroll
            for (int rr = 0; rr < 4; ++rr) {
                const float kq = ksb[m0 + 16*mt + 4*g + rr];
                const float p  = exp2f(d[rr] * C_AB - kq) * inv_l;
                pl[nl][16*mt + 4*g + rr] = (__bf16)p;
            }
        }
        const bf16x8 pb = *(const bf16x8*)&pl[nl][8 * g];
#pragma unroll
        for (int ct = 0; ct < 8; ++ct) {
            const float* vp = mvb + (size_t)(cb + 16*ct + nl) * M_ + (m0 + 8*g);
            const float4 v0 = *(const float4*)vp;
            const float4 v1 = *(const float4*)(vp + 4);
            bf16x8 vaf;
            vaf[0]=(__bf16)v0.x; vaf[1]=(__bf16)v0.y; vaf[2]=(__bf16)v0.z; vaf[3]=(__bf16)v0.w;
            vaf[4]=(__bf16)v1.x; vaf[5]=(__bf16)v1.y; vaf[6]=(__bf16)v1.z; vaf[7]=(__bf16)v1.w;
            acc[ct] = mfma16(vaf, pb, acc[ct]);
        }
    }
    float* ob = out + (size_t)b * (2 * CV_) * N_;
#pragma unroll
    for (int ct = 0; ct < 8; ++ct)
#pragma unroll
      for (int rr = 0; rr < 4; ++rr)
        ob[(size_t)(cb + 16*ct + 4*g + rr) * N_ + (nb + nl)] = acc[ct][rr];
}

// ===========================================================================
// Shared tail: conv gate + finalize (round-1, verified)
// ===========================================================================

__global__ __launch_bounds__(256) void conv_gate_kernel(const float* __restrict__ out_mem,
                                                        const float* __restrict__ qv,
                                                        const float* __restrict__ mask,
                                                        const float* __restrict__ cw,
                                                        const float* __restrict__ cbias,
                                                        float* __restrict__ gate_ws) {
    const int p = blockIdx.x;
    const int b = blockIdx.y;
    const int y = p / W_, x = p % W_;
    const int tid = threadIdx.x;
    float partial = 0.f;
    for (int c = tid; c < 2 * CV_ + 1; c += 256) {
        const float* src;
        if (c < CV_)          src = out_mem + ((size_t)b * (2*CV_) + c) * N_;
        else if (c < 2 * CV_) src = qv + ((size_t)b * CV_ + (c - CV_)) * N_;
        else                  src = mask + (size_t)b * N_;
        const float* wr = cw + c * 9;
#pragma unroll
        for (int dy = -1; dy <= 1; ++dy) {
            const int yy = y + dy;
            if (yy < 0 || yy >= H_) continue;
#pragma unroll
            for (int dx = -1; dx <= 1; ++dx) {
                const int xx = x + dx;
                if (xx < 0 || xx >= W_) continue;
                partial += src[yy * W_ + xx] * wr[(dy+1)*3 + (dx+1)];
            }
        }
    }
    partial += __shfl_xor(partial, 1);  partial += __shfl_xor(partial, 2);
    partial += __shfl_xor(partial, 4);  partial += __shfl_xor(partial, 8);
    partial += __shfl_xor(partial, 16); partial += __shfl_xor(partial, 32);
    __shared__ float red[4];
    if ((tid & 63) == 0) red[tid >> 6] = partial;
    __syncthreads();
    if (tid == 0) {
        const float s = red[0] + red[1] + red[2] + red[3] + cbias[0];
        gate_ws[(size_t)b * N_ + p] = 1.f / (1.f + exp2f(-s * 1.44269504f));
    }
}

__global__ __launch_bounds__(256) void finalize_kernel(const float* __restrict__ qv,
                                                       const float* __restrict__ gate_ws,
                                                       float* __restrict__ out) {
    const int idx = blockIdx.x * 256 + threadIdx.x;
    const int n4 = N_ / 4;
    const int pos4 = idx % n4;
    const int row  = idx / n4;
    const int b = row >> 10, ch = row & 1023;
    const float4 gv = *(const float4*)(gate_ws + (size_t)b * N_ + pos4 * 4);
    float* op = out + (size_t)row * N_ + pos4 * 4;
    float4 v;
    if (ch < CV_) v = *(const float4*)op;
    else          v = *(const float4*)(qv + ((size_t)b * CV_ + (ch - CV_)) * N_ + pos4 * 4);
    v.x *= gv.x; v.y *= gv.y; v.z *= gv.z; v.w *= gv.w;
    *(float4*)op = v;
}

// ===========================================================================
extern "C" void kernel_launch(void* const* d_in, const int* in_sizes, int n_in,
                              void* d_out, int out_size, void* d_ws, size_t ws_size,
                              hipStream_t stream) {
    (void)in_sizes; (void)n_in; (void)out_size;
    const float* mk    = (const float*)d_in[0];
    const float* qk    = (const float*)d_in[1];
    const float* mv    = (const float*)d_in[2];
    const float* qv    = (const float*)d_in[3];
    const float* mask  = (const float*)d_in[4];
    const float* cw    = (const float*)d_in[5];
    const float* cbias = (const float*)d_in[6];
    float* outf = (float*)d_out;

    // main-path workspace layout (bytes)
    const size_t kbf_b   = (size_t)B_ * M_ * 64 * 2;        //  4,718,592
    const size_t vbf_b   = (size_t)B_ * CV_ * M_ * 2;       // 37,748,736
    const size_t ksq_b   = (size_t)B_ * M_ * 4;             //    147,456
    const size_t partO_b = (size_t)SSPLIT * B_ * CV_ * N_ * 4; // 37,748,736
    const size_t partD_b = (size_t)SSPLIT * B_ * N_ * 4;    //     73,728
    const size_t gate_b  = (size_t)B_ * N_ * 4;             //     18,432
    const size_t REQUIRED = kbf_b + vbf_b + ksq_b + partO_b + partD_b + gate_b;

    if (ws_size >= REQUIRED) {
        char* p = (char*)d_ws;
        __bf16* kbf   = (__bf16*)p;            p += kbf_b;
        __bf16* vbf   = (__bf16*)p;            p += vbf_b;
        float*  ksq_s = (float*)p;             p += ksq_b;
        float*  partO = (float*)p;             p += partO_b;
        float*  partD = (float*)p;             p += partD_b;
        float*  gate_ws = (float*)p;

        prep_k<<<dim3(B_ * M_ / 256), 256, 0, stream>>>(mk, kbf, ksq_s);
        prep_v<<<dim3(B_ * CV_ * M_ / 8 / 256), 256, 0, stream>>>(mv, vbf);
        flash_kernel<<<dim3(72 * SSPLIT * B_), 256, 0, stream>>>(kbf, qk, vbf, ksq_s, partO, partD);
        reduce_kernel<<<dim3(B_ * CV_ * (N_ / 4) / 256), 256, 0, stream>>>(partO, partD, outf);
        conv_gate_kernel<<<dim3(N_, B_), 256, 0, stream>>>(outf, qv, mask, cw, cbias, gate_ws);
        finalize_kernel<<<dim3((B_ * 2 * CV_ * N_ / 4) / 256), 256, 0, stream>>>(qv, gate_ws, outf);
    } else {
        // fallback: round-1 verified path (tiny workspace)
        float* ksq_s   = (float*)d_ws;
        float* inv_ws  = ksq_s + (size_t)B_ * M_;
        float* gate_ws = inv_ws + (size_t)B_ * N_;
        ksq_kernel   <<<dim3(B_ * M_ / 256), 256, 0, stream>>>(mk, ksq_s);
        stats_kernel <<<dim3(N_ / 32, B_),   256, 0, stream>>>(mk, qk, ksq_s, inv_ws);
        pv_kernel    <<<dim3(N_ / 32, 4, B_), 128, 0, stream>>>(mk, qk, mv, ksq_s, inv_ws, outf);
        conv_gate_kernel<<<dim3(N_, B_), 256, 0, stream>>>(outf, qv, mask, cw, cbias, gate_ws);
        finalize_kernel <<<dim3((B_ * 2 * CV_ * N_ / 4) / 256), 256, 0, stream>>>(qv, gate_ws, outf);
    }
}

// Round 3
// 564.480 us; speedup vs baseline: 6.0027x; 1.2258x over previous
//
#include <hip/hip_runtime.h>

// Problem constants (fixed by setup_inputs)
#define B_  2
#define CK_ 64
#define CV_ 512
#define H_  48
#define W_  48
#define M_  18432   // T*H*W
#define N_  2304    // H*W

#define SSPLIT 8
#define MSEG   (M_ / SSPLIT)   // 2304

typedef __bf16 bf16x8 __attribute__((ext_vector_type(8)));
typedef __bf16 bf16x4 __attribute__((ext_vector_type(4)));
typedef float  f32x4  __attribute__((ext_vector_type(4)));

// exp2-domain constants: logit = (2*ab - |k|^2)/sqrt(64); exp(l) = 2^(ab*C_AB - ksq*C_KSQ)
#define C_AB  0.36067376f
#define C_KSQ 0.18033688f

__device__ inline f32x4 mfma16(bf16x8 a, bf16x8 b, f32x4 c) {
    return __builtin_amdgcn_mfma_f32_16x16x32_bf16(a, b, c, 0, 0, 0);
}

// ---------------------------------------------------------------------------
// prep_k: kbf[b][m][k] = bf16(mk[b][k][m]) (m-major), ksq_s[b][m] = |k|^2 * C_KSQ
// ---------------------------------------------------------------------------
__global__ __launch_bounds__(256) void prep_k(const float* __restrict__ mk,
                                              __bf16* __restrict__ kbf,
                                              float* __restrict__ ksq_s) {
    const int idx = blockIdx.x * 256 + threadIdx.x;   // B*M threads
    const int b = idx / M_, m = idx % M_;
    const float* src = mk + (size_t)b * CK_ * M_ + m;
    __bf16* dst = kbf + (size_t)idx * 64;
    float s = 0.f;
#pragma unroll
    for (int c = 0; c < 8; ++c) {
        bf16x8 o;
#pragma unroll
        for (int j = 0; j < 8; ++j) {
            float v = src[(size_t)(8 * c + j) * M_];
            s += v * v;
            o[j] = (__bf16)v;
        }
        *(bf16x8*)(dst + 8 * c) = o;
    }
    ksq_s[idx] = s * C_KSQ;
}

// ---------------------------------------------------------------------------
// prep_v: f32 -> bf16 stream, same [b][c][m] layout
// ---------------------------------------------------------------------------
__global__ __launch_bounds__(256) void prep_v(const float* __restrict__ mv,
                                              __bf16* __restrict__ vbf) {
    const int idx = blockIdx.x * 256 + threadIdx.x;   // B*CV*M/8 threads
    const float4* s4 = (const float4*)mv + (size_t)idx * 2;
    const float4 a = s4[0], c = s4[1];
    bf16x8 o;
    o[0]=(__bf16)a.x; o[1]=(__bf16)a.y; o[2]=(__bf16)a.z; o[3]=(__bf16)a.w;
    o[4]=(__bf16)c.x; o[5]=(__bf16)c.y; o[6]=(__bf16)c.z; o[7]=(__bf16)c.w;
    ((bf16x8*)vbf)[idx] = o;
}

// ---------------------------------------------------------------------------
// flash2: BARRIER-FREE flash attention partial.
// One wave = 32 queries x 128 channels x one M/8 segment. K read direct from
// global (m-major bf16, per-lane contiguous 16B), P redistributed through a
// private per-wave LDS tile (same-wave RAW only -> no __syncthreads at all).
// Accumulates unnormalized O (bf16 out) + denominator (logits bounded, no
// running max needed).
// ---------------------------------------------------------------------------
__global__ __launch_bounds__(256) void flash2_kernel(const __bf16* __restrict__ kbf,
                                                     const float* __restrict__ qk,
                                                     const __bf16* __restrict__ vbf,
                                                     const float* __restrict__ ksq_s,
                                                     __bf16* __restrict__ partO,
                                                     float* __restrict__ partD) {
    const int tid = threadIdx.x;
    const int w = tid >> 6, lane = tid & 63, g = lane >> 4, nl = lane & 15;

    // XCD-chunked decomposition: 64 groups of 72 waves (18 blocks); the 72
    // waves of a group share one (cs,s,b) V-segment -> one XCD's L2.
    const int bid = blockIdx.x;            // 0..1151
    const int xcd = bid & 7;               // default round-robin XCD mapping
    const int ixc = bid >> 3;              // 0..143
    const int grp = ixc / 18;              // 0..7
    const int blk = ixc % 18;              // 0..17
    const int G   = xcd * 8 + grp;         // 0..63
    const int cs  = G & 3;
    const int sb  = G >> 2;                // 0..15
    const int s   = sb & 7;
    const int b   = sb >> 3;
    const int nt  = blk * 4 + w;           // 0..71

    const int n0 = nt * 32;
    const int cw = cs * 128;
    const int m_base = s * MSEG;

    __shared__ __align__(16) __bf16 Pl[4][32][40];   // per-wave [n][m] tile, pad->2-way banks
    __bf16 (*pl)[40] = Pl[w];

    // Q B-frags (once per wave): col = n, k = 32ks+8g+i
    const float* qkb = qk + (size_t)b * CK_ * N_;
    bf16x8 qf[2][2];
#pragma unroll
    for (int ns = 0; ns < 2; ++ns)
#pragma unroll
      for (int ks = 0; ks < 2; ++ks)
#pragma unroll
        for (int i = 0; i < 8; ++i)
            qf[ns][ks][i] = (__bf16)qkb[(size_t)(32*ks + 8*g + i) * N_ + (n0 + 16*ns + nl)];

    const __bf16* kb  = kbf + (size_t)b * M_ * 64;
    const __bf16* vb  = vbf + ((size_t)b * CV_ + cw) * M_;
    const float*  ksb = ksq_s + (size_t)b * M_;

    f32x4 acc[8][2];
#pragma unroll
    for (int ct = 0; ct < 8; ++ct) { acc[ct][0] = (f32x4){0,0,0,0}; acc[ct][1] = (f32x4){0,0,0,0}; }
    float den0 = 0.f, den1 = 0.f;

    for (int ms = 0; ms < MSEG / 32; ++ms) {          // 72 iters, no barriers
        const int m0 = m_base + ms * 32;

        // V^T A-frags: row c = 16ct+nl, k(m) = 8g+i (contiguous 16B)
        bf16x8 va[8];
#pragma unroll
        for (int ct = 0; ct < 8; ++ct)
            va[ct] = *(const bf16x8*)(vb + (size_t)(16*ct + nl) * M_ + m0 + 8*g);

        // K A-frags direct from global m-major: row m = m0+16mt+nl, k = 32ks+8g+i
        bf16x8 af[2][2];
#pragma unroll
        for (int mt = 0; mt < 2; ++mt)
#pragma unroll
          for (int ks = 0; ks < 2; ++ks)
            af[mt][ks] = *(const bf16x8*)(kb + (size_t)(m0 + 16*mt + nl) * 64 + 32*ks + 8*g);

        const float4 kq0 = *(const float4*)(ksb + m0 + 4*g);
        const float4 kq1 = *(const float4*)(ksb + m0 + 16 + 4*g);
        const float kqa[2][4] = {{kq0.x, kq0.y, kq0.z, kq0.w},
                                 {kq1.x, kq1.y, kq1.z, kq1.w}};

        // QK^T: d[mt][ns], rows = m, cols = n
        f32x4 d[2][2];
#pragma unroll
        for (int mt = 0; mt < 2; ++mt)
#pragma unroll
          for (int ns = 0; ns < 2; ++ns) {
            f32x4 t = {0,0,0,0};
            t = mfma16(af[mt][0], qf[ns][0], t);
            t = mfma16(af[mt][1], qf[ns][1], t);
            d[mt][ns] = t;
          }

        // p = exp2(d*C_AB - ksq), accumulate denom, write P tile (C-layout)
#pragma unroll
        for (int mt = 0; mt < 2; ++mt) {
            bf16x4 pw0, pw1;
#pragma unroll
            for (int rr = 0; rr < 4; ++rr) {
                const float p0 = __builtin_amdgcn_exp2f(d[mt][0][rr] * C_AB - kqa[mt][rr]);
                const float p1 = __builtin_amdgcn_exp2f(d[mt][1][rr] * C_AB - kqa[mt][rr]);
                den0 += p0; den1 += p1;
                pw0[rr] = (__bf16)p0; pw1[rr] = (__bf16)p1;
            }
            *(bf16x4*)&pl[nl][16*mt + 4*g]      = pw0;
            *(bf16x4*)&pl[16 + nl][16*mt + 4*g] = pw1;
        }

        // P B-frags (same-wave LDS RAW, lgkmcnt only) + PV
        const bf16x8 pb0 = *(const bf16x8*)&pl[nl][8*g];
        const bf16x8 pb1 = *(const bf16x8*)&pl[16 + nl][8*g];
#pragma unroll
        for (int ct = 0; ct < 8; ++ct) {
            acc[ct][0] = mfma16(va[ct], pb0, acc[ct][0]);
            acc[ct][1] = mfma16(va[ct], pb1, acc[ct][1]);
        }
    }

    // denominators: reduce over g (m-row groups); identical across cs -> cs==0 writes
    den0 += __shfl_xor(den0, 16);  den0 += __shfl_xor(den0, 32);
    den1 += __shfl_xor(den1, 16);  den1 += __shfl_xor(den1, 32);
    if (cs == 0 && lane < 16) {
        partD[(size_t)(s * B_ + b) * N_ + n0 + nl]      = den0;
        partD[(size_t)(s * B_ + b) * N_ + n0 + 16 + nl] = den1;
    }

    // unnormalized partial O in bf16
    __bf16* po = partO + (((size_t)(s * B_ + b) * CV_ + cw) * N_) + n0;
#pragma unroll
    for (int ct = 0; ct < 8; ++ct)
#pragma unroll
      for (int rr = 0; rr < 4; ++rr) {
        po[(size_t)(16*ct + 4*g + rr) * N_ + nl]      = (__bf16)acc[ct][0][rr];
        po[(size_t)(16*ct + 4*g + rr) * N_ + 16 + nl] = (__bf16)acc[ct][1][rr];
      }
}

// ---------------------------------------------------------------------------
// reduce: mem[b][c][n] = sum_s partO / sum_s partD  -> d_out channels 0..511
// ---------------------------------------------------------------------------
__global__ __launch_bounds__(256) void reduce_kernel(const __bf16* __restrict__ partO,
                                                     const float* __restrict__ partD,
                                                     float* __restrict__ out) {
    const int idx = blockIdx.x * 256 + threadIdx.x;   // B*CV*(N/8) threads
    const int n8 = idx % (N_ / 8);
    const int c  = (idx / (N_ / 8)) % CV_;
    const int b  = idx / ((N_ / 8) * CV_);
    float o[8] = {0,0,0,0,0,0,0,0};
    float dd[8] = {0,0,0,0,0,0,0,0};
#pragma unroll
    for (int s = 0; s < SSPLIT; ++s) {
        const bf16x8 ov = *(const bf16x8*)(partO + (((size_t)(s*B_+b)*CV_ + c) * N_) + n8*8);
        const float4 d0 = *(const float4*)(partD + (size_t)(s*B_+b)*N_ + n8*8);
        const float4 d1 = *(const float4*)(partD + (size_t)(s*B_+b)*N_ + n8*8 + 4);
#pragma unroll
        for (int j = 0; j < 8; ++j) o[j] += (float)ov[j];
        dd[0]+=d0.x; dd[1]+=d0.y; dd[2]+=d0.z; dd[3]+=d0.w;
        dd[4]+=d1.x; dd[5]+=d1.y; dd[6]+=d1.z; dd[7]+=d1.w;
    }
    float* op = out + ((size_t)b * (2*CV_) + c) * N_ + n8*8;
#pragma unroll
    for (int j = 0; j < 8; ++j) op[j] = o[j] / dd[j];
}

// ---------------------------------------------------------------------------
// conv_r: R_j[cc][b][p] = sum_{c in chunk cc} in[c][p] * w[c][j], coalesced
// along p. cc 0..3 -> mem (out rows), 4..7 -> qv, 8 -> mask.
// ---------------------------------------------------------------------------
__global__ __launch_bounds__(256) void conv_r_kernel(const float* __restrict__ outf,
                                                     const float* __restrict__ qv,
                                                     const float* __restrict__ mask,
                                                     const float* __restrict__ cw,
                                                     float* __restrict__ Rp) {
    const int p  = blockIdx.x * 256 + threadIdx.x;   // 0..N-1
    const int cc = blockIdx.y;                        // 0..8
    const int b  = blockIdx.z;
    float r[9] = {0,0,0,0,0,0,0,0,0};
    if (cc < 8) {
        const float* src = (cc < 4) ? outf + ((size_t)b * (2*CV_) + cc * 128) * N_
                                    : qv   + ((size_t)b * CV_ + (cc - 4) * 128) * N_;
        const float* wb = cw + (size_t)cc * 128 * 9;
        for (int c = 0; c < 128; ++c) {
            const float v = src[(size_t)c * N_ + p];
#pragma unroll
            for (int j = 0; j < 9; ++j) r[j] += v * wb[c * 9 + j];
        }
    } else {
        const float v = mask[(size_t)b * N_ + p];
#pragma unroll
        for (int j = 0; j < 9; ++j) r[j] = v * cw[1024 * 9 + j];
    }
#pragma unroll
    for (int j = 0; j < 9; ++j)
        Rp[(((size_t)cc * 9 + j) * B_ + b) * N_ + p] = r[j];
}

// ---------------------------------------------------------------------------
// gate: gate[b][p] = sigmoid( sum_j sum_cc Rp[cc][j][b][neighbor_j(p)] + bias )
// ---------------------------------------------------------------------------
__global__ __launch_bounds__(256) void gate_kernel(const float* __restrict__ Rp,
                                                   const float* __restrict__ cbias,
                                                   float* __restrict__ gate_ws) {
    const int p = blockIdx.x * 256 + threadIdx.x;    // 0..N-1
    const int b = blockIdx.y;
    const int y = p / W_, x = p % W_;
    float sum = cbias[0];
#pragma unroll
    for (int dy = -1; dy <= 1; ++dy) {
        const int yy = y + dy;
        if (yy < 0 || yy >= H_) continue;
#pragma unroll
        for (int dx = -1; dx <= 1; ++dx) {
            const int xx = x + dx;
            if (xx < 0 || xx >= W_) continue;
            const int j = (dy + 1) * 3 + (dx + 1);
            const int q = yy * W_ + xx;
#pragma unroll
            for (int cc = 0; cc < 9; ++cc)
                sum += Rp[(((size_t)cc * 9 + j) * B_ + b) * N_ + q];
        }
    }
    gate_ws[(size_t)b * N_ + p] = 1.f / (1.f + __builtin_amdgcn_exp2f(-sum * 1.44269504f));
}

// ---------------------------------------------------------------------------
// finalize: out[b][ch][n] = (ch<512 ? mem : qv) * gate[b][n]
// ---------------------------------------------------------------------------
__global__ __launch_bounds__(256) void finalize_kernel(const float* __restrict__ qv,
                                                       const float* __restrict__ gate_ws,
                                                       float* __restrict__ out) {
    const int idx = blockIdx.x * 256 + threadIdx.x;
    const int n4 = N_ / 4;
    const int pos4 = idx % n4;
    const int row  = idx / n4;
    const int b = row >> 10, ch = row & 1023;
    const float4 gv = *(const float4*)(gate_ws + (size_t)b * N_ + pos4 * 4);
    float* op = out + (size_t)row * N_ + pos4 * 4;
    float4 v;
    if (ch < CV_) v = *(const float4*)op;
    else          v = *(const float4*)(qv + ((size_t)b * CV_ + (ch - CV_)) * N_ + pos4 * 4);
    v.x *= gv.x; v.y *= gv.y; v.z *= gv.z; v.w *= gv.w;
    *(float4*)op = v;
}

// ===========================================================================
extern "C" void kernel_launch(void* const* d_in, const int* in_sizes, int n_in,
                              void* d_out, int out_size, void* d_ws, size_t ws_size,
                              hipStream_t stream) {
    (void)in_sizes; (void)n_in; (void)out_size; (void)ws_size;
    const float* mk    = (const float*)d_in[0];
    const float* qk    = (const float*)d_in[1];
    const float* mv    = (const float*)d_in[2];
    const float* qv    = (const float*)d_in[3];
    const float* mask  = (const float*)d_in[4];
    const float* cw    = (const float*)d_in[5];
    const float* cbias = (const float*)d_in[6];
    float* outf = (float*)d_out;

    // workspace layout (bytes) — total 80,529,408 (same footprint class as r2)
    const size_t kbf_b   = (size_t)B_ * M_ * 64 * 2;             //  4,718,592 (reused as Rp later)
    const size_t vbf_b   = (size_t)B_ * CV_ * M_ * 2;            // 37,748,736
    const size_t ksq_b   = (size_t)B_ * M_ * 4;                  //    147,456
    const size_t partO_b = (size_t)SSPLIT * B_ * CV_ * N_ * 2;   // 37,748,736 (bf16)
    const size_t partD_b = (size_t)SSPLIT * B_ * N_ * 4;         //    147,456

    char* pw = (char*)d_ws;
    __bf16* kbf   = (__bf16*)pw;
    float*  Rp    = (float*)pw;            // overlays kbf (dead after flash2); 1.49 MB < 4.7 MB
    pw += kbf_b;
    __bf16* vbf   = (__bf16*)pw;           pw += vbf_b;
    float*  ksq_s = (float*)pw;            pw += ksq_b;
    __bf16* partO = (__bf16*)pw;           pw += partO_b;
    float*  partD = (float*)pw;            pw += partD_b;
    float*  gate_ws = (float*)pw;

    prep_k<<<dim3(B_ * M_ / 256), 256, 0, stream>>>(mk, kbf, ksq_s);
    prep_v<<<dim3(B_ * CV_ * M_ / 8 / 256), 256, 0, stream>>>(mv, vbf);
    flash2_kernel<<<dim3(1152), 256, 0, stream>>>(kbf, qk, vbf, ksq_s, partO, partD);
    reduce_kernel<<<dim3(B_ * CV_ * (N_ / 8) / 256), 256, 0, stream>>>(partO, partD, outf);
    conv_r_kernel<<<dim3(N_ / 256, 9, B_), 256, 0, stream>>>(outf, qv, mask, cw, Rp);
    gate_kernel<<<dim3(N_ / 256, B_), 256, 0, stream>>>(Rp, cbias, gate_ws);
    finalize_kernel<<<dim3((B_ * 2 * CV_ * N_ / 4) / 256), 256, 0, stream>>>(qv, gate_ws, outf);
}

// Round 4
// 558.810 us; speedup vs baseline: 6.0636x; 1.0101x over previous
//
#include <hip/hip_runtime.h>

// Problem constants (fixed by setup_inputs)
#define B_  2
#define CK_ 64
#define CV_ 512
#define H_  48
#define W_  48
#define M_  18432   // T*H*W
#define N_  2304    // H*W

#define SSPLIT 8
#define MSEG   (M_ / SSPLIT)   // 2304

typedef __bf16 bf16x8 __attribute__((ext_vector_type(8)));
typedef float  f32x4  __attribute__((ext_vector_type(4)));
typedef float  f32x16 __attribute__((ext_vector_type(16)));
typedef unsigned int u32x4 __attribute__((ext_vector_type(4)));

// logit = (2*ab - |k|^2)/sqrt(64); exp2 domain:
// arg = ab*(2*log2e/8) - ksq*(log2e/8). Q is pre-scaled by C2Q at bf16-cast,
// ksq is pre-scaled by C_KSQ and stored as a bf16 hi+lo pair.
#define C2Q   0.36067376f
#define C_KSQ 0.18033688f

__device__ inline f32x16 mfma32(bf16x8 a, bf16x8 b, f32x16 c) {
    return __builtin_amdgcn_mfma_f32_32x32x16_bf16(a, b, c, 0, 0, 0);
}

__device__ inline unsigned pack_bf16(float lo, float hi) {
    union { __bf16 h; unsigned short u; } a, b;
    a.h = (__bf16)lo; b.h = (__bf16)hi;
    return ((unsigned)b.u << 16) | a.u;   // compiler emits v_cvt_pk / v_perm
}

// ---------------------------------------------------------------------------
// prep_k: kbf[b][m][k] = bf16(mk[b][k][m]) (m-major, stride 64), plus
// ksq2[b][m] = packed u32 {hi16: lo-part, lo16: hi-part} of C_KSQ*|k|^2 as
// bf16 hi + bf16 residual lo (so the MFMA-side subtraction is ~exact).
// ---------------------------------------------------------------------------
__global__ __launch_bounds__(256) void prep_k(const float* __restrict__ mk,
                                              __bf16* __restrict__ kbf,
                                              unsigned* __restrict__ ksq2) {
    const int idx = blockIdx.x * 256 + threadIdx.x;   // B*M threads
    const int b = idx / M_, m = idx % M_;
    const float* src = mk + (size_t)b * CK_ * M_ + m;
    __bf16* dst = kbf + (size_t)idx * 64;
    float s = 0.f;
#pragma unroll
    for (int c = 0; c < 8; ++c) {
        bf16x8 o;
#pragma unroll
        for (int j = 0; j < 8; ++j) {
            float v = src[(size_t)(8 * c + j) * M_];
            s += v * v;
            o[j] = (__bf16)v;
        }
        *(bf16x8*)(dst + 8 * c) = o;
    }
    const float tot = s * C_KSQ;
    const float hi = (float)(__bf16)tot;
    const float lo = tot - hi;
    ksq2[idx] = pack_bf16(hi, lo);   // elem0 = hi, elem1 = lo
}

// ---------------------------------------------------------------------------
// prep_v: f32 -> bf16 stream, same [b][c][m] layout
// ---------------------------------------------------------------------------
__global__ __launch_bounds__(256) void prep_v(const float* __restrict__ mv,
                                              __bf16* __restrict__ vbf) {
    const int idx = blockIdx.x * 256 + threadIdx.x;   // B*CV*M/8 threads
    const float4* s4 = (const float4*)mv + (size_t)idx * 2;
    const float4 a = s4[0], c = s4[1];
    bf16x8 o;
    o[0]=(__bf16)a.x; o[1]=(__bf16)a.y; o[2]=(__bf16)a.z; o[3]=(__bf16)a.w;
    o[4]=(__bf16)c.x; o[5]=(__bf16)c.y; o[6]=(__bf16)c.z; o[7]=(__bf16)c.w;
    ((bf16x8*)vbf)[idx] = o;
}

// ---------------------------------------------------------------------------
// flash3: barrier-free AND LDS-free flash partial, 32x32x16 MFMA.
// One wave = 32 queries x 128 channels x one M/8 segment.
//  - QK^T swapped (A=K rows=m, B=Q' cols=n): 4 k-step MFMAs + 1 rank-2 MFMA
//    that subtracts ksq (A slots {hi,lo} x B slots {-1,-1}) -> D = exp2-arg.
//  - p = exp2(D); P redistribution to the PV B-frag layout entirely
//    in-register: 8 pack_bf16 + 4 v_permlane32_swap_b32 (T12 pattern).
//  - PV: V^T as A operand (rows=c), acc 4x f32x16 (128 channels x 32 n).
// ---------------------------------------------------------------------------
__global__ __launch_bounds__(256) void flash3_kernel(const __bf16* __restrict__ kbf,
                                                     const float* __restrict__ qk,
                                                     const __bf16* __restrict__ vbf,
                                                     const unsigned* __restrict__ ksq2,
                                                     __bf16* __restrict__ partO,
                                                     float* __restrict__ partD) {
    const int tid = threadIdx.x;
    const int w = tid >> 6, lane = tid & 63;
    const int l31 = lane & 31, h = lane >> 5;

    // XCD-chunked decomposition: 64 groups of 72 waves (18 blocks); the 72
    // waves of a group share one (cs,s,b) K/V-segment -> one XCD's L2.
    const int bid = blockIdx.x;            // 0..1151
    const int xcd = bid & 7;
    const int ixc = bid >> 3;              // 0..143
    const int grp = ixc / 18;
    const int blk = ixc % 18;
    const int G   = xcd * 8 + grp;         // 0..63
    const int cs  = G & 3;
    const int sb  = G >> 2;
    const int s   = sb & 7, b = sb >> 3;
    const int nt  = blk * 4 + w;           // 0..71

    const int n0 = nt * 32;
    const int cw = cs * 128;
    const int m_base = s * MSEG;

    // Q' B-frags (once per wave): col = n0+l31, k = 16ks+8h+i, scaled by C2Q
    const float* qkb = qk + (size_t)b * CK_ * N_;
    bf16x8 qf[4];
#pragma unroll
    for (int ks = 0; ks < 4; ++ks)
#pragma unroll
      for (int i = 0; i < 8; ++i)
        qf[ks][i] = (__bf16)(qkb[(size_t)(16*ks + 8*h + i) * N_ + (n0 + l31)] * C2Q);

    // constant B-frag: -1.0bf16 at elements {0,1} (k slots {0,1} per half;
    // the other half's A elements are zero, so no cross-talk)
    const u32x4 bneg_u = {0xBF80BF80u, 0u, 0u, 0u};
    const bf16x8 bneg = __builtin_bit_cast(bf16x8, bneg_u);

    const __bf16*   kb  = kbf  + (size_t)b * M_ * 64;
    const __bf16*   vb  = vbf  + ((size_t)b * CV_ + cw) * M_;
    const unsigned* ksb = ksq2 + (size_t)b * M_;

    f32x16 acc[4];
#pragma unroll
    for (int ct = 0; ct < 4; ++ct)
#pragma unroll
      for (int r = 0; r < 16; ++r) acc[ct][r] = 0.f;
    float den = 0.f;

    for (int ms = 0; ms < MSEG / 32; ++ms) {          // 72 iters, no barriers, no LDS
        const int m0 = m_base + ms * 32;

        // K A-frags: row m = m0+l31, k = 16ks+8h+i (16B contiguous per lane)
        const __bf16* krow = kb + (size_t)(m0 + l31) * 64;
        bf16x8 af0 = *(const bf16x8*)(krow + 8*h);
        bf16x8 af1 = *(const bf16x8*)(krow + 16 + 8*h);
        bf16x8 af2 = *(const bf16x8*)(krow + 32 + 8*h);
        bf16x8 af3 = *(const bf16x8*)(krow + 48 + 8*h);
        // ksq rank-2 A-frag: {hi, lo} at k slots {0,1}, h=0 half only
        const unsigned kq2 = ksb[m0 + l31];
        u32x4 a4u = { h ? 0u : kq2, 0u, 0u, 0u };
        const bf16x8 af4 = __builtin_bit_cast(bf16x8, a4u);

        // D = C2Q*ab - C_KSQ*ksq  (exp2-arg), rows m, cols n
        f32x16 d;
#pragma unroll
        for (int r = 0; r < 16; ++r) d[r] = 0.f;
        d = mfma32(af0, qf[0], d);
        d = mfma32(af1, qf[1], d);
        d = mfma32(af2, qf[2], d);
        d = mfma32(af3, qf[3], d);
        d = mfma32(af4, bneg, d);

        // p = exp2(d); pack m-pairs; accumulate denominator
        unsigned wpk[8];
#pragma unroll
        for (int j = 0; j < 8; ++j) {
            const float pa = __builtin_amdgcn_exp2f(d[2*j]);
            const float pb = __builtin_amdgcn_exp2f(d[2*j+1]);
            den += pa + pb;
            wpk[j] = pack_bf16(pa, pb);   // m-pair at 8*(j>>1)+4h+2*(j&1)
        }

        // P B-frags via permlane32_swap: per ks, slots {0,2} = swap(w[4ks],
        // w[4ks+2]); slots {1,3} = swap(w[4ks+1], w[4ks+3]).
        bf16x8 pb[2];
#pragma unroll
        for (int ks = 0; ks < 2; ++ks) {
            unsigned a0 = wpk[4*ks],     b0 = wpk[4*ks+2];
            unsigned a1 = wpk[4*ks+1],   b1 = wpk[4*ks+3];
            asm volatile("v_permlane32_swap_b32 %0, %1" : "+v"(a0), "+v"(b0));
            asm volatile("v_permlane32_swap_b32 %0, %1" : "+v"(a1), "+v"(b1));
            u32x4 pu = {a0, a1, b0, b1};
            pb[ks] = __builtin_bit_cast(bf16x8, pu);
        }

        // PV: V^T A-frags (row c = 32ct+l31, k(m) = 16ks+8h+i), 8 MFMA
        const __bf16* vrow = vb + (size_t)l31 * M_ + m0 + 8*h;
#pragma unroll
        for (int ct = 0; ct < 4; ++ct) {
            const __bf16* vp = vrow + (size_t)(32*ct) * M_;
            const bf16x8 va0 = *(const bf16x8*)(vp);
            const bf16x8 va1 = *(const bf16x8*)(vp + 16);
            acc[ct] = mfma32(va0, pb[0], acc[ct]);
            acc[ct] = mfma32(va1, pb[1], acc[ct]);
        }
    }

    // denominator: lane holds sum over its 16 m-rows; add other half
    den += __shfl_xor(den, 32);
    if (cs == 0 && lane < 32)
        partD[(size_t)(s * B_ + b) * N_ + n0 + l31] = den;

    // unnormalized partial O in bf16: c = cw + 32ct + (r&3)+8*(r>>2)+4h
    __bf16* po = partO + (((size_t)(s * B_ + b) * CV_ + cw) * N_) + n0 + l31;
#pragma unroll
    for (int ct = 0; ct < 4; ++ct)
#pragma unroll
      for (int r = 0; r < 16; ++r) {
        const int crow = 32*ct + (r & 3) + 8*(r >> 2) + 4*h;
        po[(size_t)crow * N_] = (__bf16)acc[ct][r];
      }
}

// ---------------------------------------------------------------------------
// reduce: mem[b][c][n] = sum_s partO / sum_s partD  -> d_out channels 0..511
// ---------------------------------------------------------------------------
__global__ __launch_bounds__(256) void reduce_kernel(const __bf16* __restrict__ partO,
                                                     const float* __restrict__ partD,
                                                     float* __restrict__ out) {
    const int idx = blockIdx.x * 256 + threadIdx.x;   // B*CV*(N/8) threads
    const int n8 = idx % (N_ / 8);
    const int c  = (idx / (N_ / 8)) % CV_;
    const int b  = idx / ((N_ / 8) * CV_);
    float o[8] = {0,0,0,0,0,0,0,0};
    float dd[8] = {0,0,0,0,0,0,0,0};
#pragma unroll
    for (int s = 0; s < SSPLIT; ++s) {
        const bf16x8 ov = *(const bf16x8*)(partO + (((size_t)(s*B_+b)*CV_ + c) * N_) + n8*8);
        const float4 d0 = *(const float4*)(partD + (size_t)(s*B_+b)*N_ + n8*8);
        const float4 d1 = *(const float4*)(partD + (size_t)(s*B_+b)*N_ + n8*8 + 4);
#pragma unroll
        for (int j = 0; j < 8; ++j) o[j] += (float)ov[j];
        dd[0]+=d0.x; dd[1]+=d0.y; dd[2]+=d0.z; dd[3]+=d0.w;
        dd[4]+=d1.x; dd[5]+=d1.y; dd[6]+=d1.z; dd[7]+=d1.w;
    }
    float* op = out + ((size_t)b * (2*CV_) + c) * N_ + n8*8;
#pragma unroll
    for (int j = 0; j < 8; ++j) op[j] = o[j] / dd[j];
}

// ---------------------------------------------------------------------------
// conv_r: R_j[cc][b][p] = sum_{c in chunk cc} in[c][p] * w[c][j], coalesced
// along p. cc 0..3 -> mem (out rows), 4..7 -> qv, 8 -> mask.
// ---------------------------------------------------------------------------
__global__ __launch_bounds__(256) void conv_r_kernel(const float* __restrict__ outf,
                                                     const float* __restrict__ qv,
                                                     const float* __restrict__ mask,
                                                     const float* __restrict__ cw,
                                                     float* __restrict__ Rp) {
    const int p  = blockIdx.x * 256 + threadIdx.x;   // 0..N-1
    const int cc = blockIdx.y;                        // 0..8
    const int b  = blockIdx.z;
    float r[9] = {0,0,0,0,0,0,0,0,0};
    if (cc < 8) {
        const float* src = (cc < 4) ? outf + ((size_t)b * (2*CV_) + cc * 128) * N_
                                    : qv   + ((size_t)b * CV_ + (cc - 4) * 128) * N_;
        const float* wb = cw + (size_t)cc * 128 * 9;
        for (int c = 0; c < 128; ++c) {
            const float v = src[(size_t)c * N_ + p];
#pragma unroll
            for (int j = 0; j < 9; ++j) r[j] += v * wb[c * 9 + j];
        }
    } else {
        const float v = mask[(size_t)b * N_ + p];
#pragma unroll
        for (int j = 0; j < 9; ++j) r[j] = v * cw[1024 * 9 + j];
    }
#pragma unroll
    for (int j = 0; j < 9; ++j)
        Rp[(((size_t)cc * 9 + j) * B_ + b) * N_ + p] = r[j];
}

// ---------------------------------------------------------------------------
// gate: gate[b][p] = sigmoid( sum_j sum_cc Rp[cc][j][b][neighbor_j(p)] + bias )
// ---------------------------------------------------------------------------
__global__ __launch_bounds__(256) void gate_kernel(const float* __restrict__ Rp,
                                                   const float* __restrict__ cbias,
                                                   float* __restrict__ gate_ws) {
    const int p = blockIdx.x * 256 + threadIdx.x;    // 0..N-1
    const int b = blockIdx.y;
    const int y = p / W_, x = p % W_;
    float sum = cbias[0];
#pragma unroll
    for (int dy = -1; dy <= 1; ++dy) {
        const int yy = y + dy;
        if (yy < 0 || yy >= H_) continue;
#pragma unroll
        for (int dx = -1; dx <= 1; ++dx) {
            const int xx = x + dx;
            if (xx < 0 || xx >= W_) continue;
            const int j = (dy + 1) * 3 + (dx + 1);
            const int q = yy * W_ + xx;
#pragma unroll
            for (int cc = 0; cc < 9; ++cc)
                sum += Rp[(((size_t)cc * 9 + j) * B_ + b) * N_ + q];
        }
    }
    gate_ws[(size_t)b * N_ + p] = 1.f / (1.f + __builtin_amdgcn_exp2f(-sum * 1.44269504f));
}

// ---------------------------------------------------------------------------
// finalize: out[b][ch][n] = (ch<512 ? mem : qv) * gate[b][n]
// ---------------------------------------------------------------------------
__global__ __launch_bounds__(256) void finalize_kernel(const float* __restrict__ qv,
                                                       const float* __restrict__ gate_ws,
                                                       float* __restrict__ out) {
    const int idx = blockIdx.x * 256 + threadIdx.x;
    const int n4 = N_ / 4;
    const int pos4 = idx % n4;
    const int row  = idx / n4;
    const int b = row >> 10, ch = row & 1023;
    const float4 gv = *(const float4*)(gate_ws + (size_t)b * N_ + pos4 * 4);
    float* op = out + (size_t)row * N_ + pos4 * 4;
    float4 v;
    if (ch < CV_) v = *(const float4*)op;
    else          v = *(const float4*)(qv + ((size_t)b * CV_ + (ch - CV_)) * N_ + pos4 * 4);
    v.x *= gv.x; v.y *= gv.y; v.z *= gv.z; v.w *= gv.w;
    *(float4*)op = v;
}

// ===========================================================================
extern "C" void kernel_launch(void* const* d_in, const int* in_sizes, int n_in,
                              void* d_out, int out_size, void* d_ws, size_t ws_size,
                              hipStream_t stream) {
    (void)in_sizes; (void)n_in; (void)out_size; (void)ws_size;
    const float* mk    = (const float*)d_in[0];
    const float* qk    = (const float*)d_in[1];
    const float* mv    = (const float*)d_in[2];
    const float* qv    = (const float*)d_in[3];
    const float* mask  = (const float*)d_in[4];
    const float* cw    = (const float*)d_in[5];
    const float* cbias = (const float*)d_in[6];
    float* outf = (float*)d_out;

    // workspace layout (bytes) — total 80,529,408, byte-identical to round 3
    const size_t kbf_b   = (size_t)B_ * M_ * 64 * 2;             //  4,718,592 (reused as Rp later)
    const size_t vbf_b   = (size_t)B_ * CV_ * M_ * 2;            // 37,748,736
    const size_t ksq_b   = (size_t)B_ * M_ * 4;                  //    147,456 (packed u32 hi/lo)
    const size_t partO_b = (size_t)SSPLIT * B_ * CV_ * N_ * 2;   // 37,748,736 (bf16)
    const size_t partD_b = (size_t)SSPLIT * B_ * N_ * 4;         //    147,456

    char* pw = (char*)d_ws;
    __bf16* kbf   = (__bf16*)pw;
    float*  Rp    = (float*)pw;            // overlays kbf (dead after flash3); 1.49 MB < 4.7 MB
    pw += kbf_b;
    __bf16* vbf   = (__bf16*)pw;           pw += vbf_b;
    unsigned* ksq2 = (unsigned*)pw;        pw += ksq_b;
    __bf16* partO = (__bf16*)pw;           pw += partO_b;
    float*  partD = (float*)pw;            pw += partD_b;
    float*  gate_ws = (float*)pw;

    prep_k<<<dim3(B_ * M_ / 256), 256, 0, stream>>>(mk, kbf, ksq2);
    prep_v<<<dim3(B_ * CV_ * M_ / 8 / 256), 256, 0, stream>>>(mv, vbf);
    flash3_kernel<<<dim3(1152), 256, 0, stream>>>(kbf, qk, vbf, ksq2, partO, partD);
    reduce_kernel<<<dim3(B_ * CV_ * (N_ / 8) / 256), 256, 0, stream>>>(partO, partD, outf);
    conv_r_kernel<<<dim3(N_ / 256, 9, B_), 256, 0, stream>>>(outf, qv, mask, cw, Rp);
    gate_kernel<<<dim3(N_ / 256, B_), 256, 0, stream>>>(Rp, cbias, gate_ws);
    finalize_kernel<<<dim3((B_ * 2 * CV_ * N_ / 4) / 256), 256, 0, stream>>>(qv, gate_ws, outf);
}

// Round 5
// 351.024 us; speedup vs baseline: 9.6529x; 1.5919x over previous
//
#include <hip/hip_runtime.h>

// Problem constants (fixed by setup_inputs)
#define B_  2
#define CK_ 64
#define CV_ 512
#define H_  48
#define W_  48
#define M_  18432   // T*H*W
#define N_  2304    // H*W

#define SSPLIT 8
#define MSEG   (M_ / SSPLIT)   // 2304

typedef __bf16 bf16x8 __attribute__((ext_vector_type(8)));
typedef float  f32x4  __attribute__((ext_vector_type(4)));
typedef float  f32x16 __attribute__((ext_vector_type(16)));
typedef unsigned int u32x4 __attribute__((ext_vector_type(4)));

// logit = (2*ab - |k|^2)/sqrt(64); exp2 domain:
// arg = ab*(2*log2e/8) - ksq*(log2e/8). Q is pre-scaled by C2Q at bf16-cast,
// ksq is pre-scaled by C_KSQ and stored as a bf16 hi+lo pair.
#define C2Q   0.36067376f
#define C_KSQ 0.18033688f

__device__ inline f32x16 mfma32(bf16x8 a, bf16x8 b, f32x16 c) {
    return __builtin_amdgcn_mfma_f32_32x32x16_bf16(a, b, c, 0, 0, 0);
}

__device__ inline unsigned pack_bf16(float lo, float hi) {
    union { __bf16 h; unsigned short u; } a, b;
    a.h = (__bf16)lo; b.h = (__bf16)hi;
    return ((unsigned)b.u << 16) | a.u;
}

// ---------------------------------------------------------------------------
// prep_k: ktile layout so the QK A-frag load is a contiguous 1KB wave-load.
//   ktile[b][mt][ks][h][l][8] : elem = K[b][m = 32*mt + l][k = 16*ks + 8*h + i]
// Also ksq2[b][m] = packed bf16 {hi, lo} of C_KSQ*|k|^2.
// ---------------------------------------------------------------------------
__global__ __launch_bounds__(256) void prep_k(const float* __restrict__ mk,
                                              __bf16* __restrict__ ktile,
                                              unsigned* __restrict__ ksq2) {
    const int idx = blockIdx.x * 256 + threadIdx.x;   // B*M threads
    const int b = idx / M_, m = idx % M_;
    const float* src = mk + (size_t)b * CK_ * M_ + m;
    const int mt = m >> 5, l = m & 31;
    __bf16* dstb = ktile + (size_t)b * M_ * 64 + (size_t)mt * 2048 + l * 8;
    float s = 0.f;
#pragma unroll
    for (int j = 0; j < 8; ++j) {          // octet j: ks = j>>1, h = j&1
        bf16x8 o;
#pragma unroll
        for (int i = 0; i < 8; ++i) {
            float v = src[(size_t)(8 * j + i) * M_];
            s += v * v;
            o[i] = (__bf16)v;
        }
        *(bf16x8*)(dstb + (size_t)j * 256) = o;   // ((ks*2+h)*32)*8 = j*256
    }
    const float tot = s * C_KSQ;
    const float hi = (float)(__bf16)tot;
    const float lo = tot - hi;
    ksq2[idx] = pack_bf16(hi, lo);
}

// ---------------------------------------------------------------------------
// prep_v: vt[b][m16][c][16] : elem = V[b][c][m = 16*m16 + i].
// One thread = one (c, m16) cell: reads one full 64-B line, writes 32 B
// contiguous (consecutive threads -> consecutive c -> coalesced).
// ---------------------------------------------------------------------------
__global__ __launch_bounds__(256) void prep_v(const float* __restrict__ mv,
                                              __bf16* __restrict__ vt) {
    const int idx = blockIdx.x * 256 + threadIdx.x;   // B*1152*CV threads
    const int c   = idx % CV_;
    const int r   = idx / CV_;
    const int m16 = r % (M_ / 16);
    const int b   = r / (M_ / 16);
    const float4* s4 = (const float4*)(mv + ((size_t)b * CV_ + c) * M_ + m16 * 16);
    const float4 a0 = s4[0], a1 = s4[1], a2 = s4[2], a3 = s4[3];
    bf16x8 o0, o1;
    o0[0]=(__bf16)a0.x; o0[1]=(__bf16)a0.y; o0[2]=(__bf16)a0.z; o0[3]=(__bf16)a0.w;
    o0[4]=(__bf16)a1.x; o0[5]=(__bf16)a1.y; o0[6]=(__bf16)a1.z; o0[7]=(__bf16)a1.w;
    o1[0]=(__bf16)a2.x; o1[1]=(__bf16)a2.y; o1[2]=(__bf16)a2.z; o1[3]=(__bf16)a2.w;
    o1[4]=(__bf16)a3.x; o1[5]=(__bf16)a3.y; o1[6]=(__bf16)a3.z; o1[7]=(__bf16)a3.w;
    __bf16* dst = vt + ((size_t)r * CV_ + c) * 16;
    *(bf16x8*)dst = o0;
    *(bf16x8*)(dst + 8) = o1;
}

// ---------------------------------------------------------------------------
// flash3b: identical structure/math to validated flash3 (barrier-free,
// LDS-free, 32x32x16 MFMA, swapped QK, ksq-as-rank-2-MFMA, permlane32 P
// redistribution). ONLY the K/V global reads changed to the tiled layouts:
// every fragment load is now a contiguous 1KB wave-load (TA/L1-friendly).
// ---------------------------------------------------------------------------
__global__ __launch_bounds__(256) void flash3_kernel(const __bf16* __restrict__ ktile,
                                                     const float* __restrict__ qk,
                                                     const __bf16* __restrict__ vt,
                                                     const unsigned* __restrict__ ksq2,
                                                     __bf16* __restrict__ partO,
                                                     float* __restrict__ partD) {
    const int tid = threadIdx.x;
    const int w = tid >> 6, lane = tid & 63;
    const int l31 = lane & 31, h = lane >> 5;

    // XCD-chunked decomposition: 64 groups of 72 waves (18 blocks); the 72
    // waves of a group share one (cs,s,b) K/V-segment -> one XCD's L2.
    const int bid = blockIdx.x;            // 0..1151
    const int xcd = bid & 7;
    const int ixc = bid >> 3;              // 0..143
    const int grp = ixc / 18;
    const int blk = ixc % 18;
    const int G   = xcd * 8 + grp;         // 0..63
    const int cs  = G & 3;
    const int sb  = G >> 2;
    const int s   = sb & 7, b = sb >> 3;
    const int nt  = blk * 4 + w;           // 0..71

    const int n0 = nt * 32;
    const int cw = cs * 128;
    const int m_base = s * MSEG;

    // Q' B-frags (once per wave): col = n0+l31, k = 16ks+8h+i, scaled by C2Q
    const float* qkb = qk + (size_t)b * CK_ * N_;
    bf16x8 qf[4];
#pragma unroll
    for (int ks = 0; ks < 4; ++ks)
#pragma unroll
      for (int i = 0; i < 8; ++i)
        qf[ks][i] = (__bf16)(qkb[(size_t)(16*ks + 8*h + i) * N_ + (n0 + l31)] * C2Q);

    // constant B-frag: -1.0bf16 at k slots {0,1} (h=1 A-half is zero)
    const u32x4 bneg_u = {0xBF80BF80u, 0u, 0u, 0u};
    const bf16x8 bneg = __builtin_bit_cast(bf16x8, bneg_u);

    const __bf16*   kb  = ktile + (size_t)b * M_ * 64;
    const __bf16*   vb  = vt    + (size_t)b * M_ * CV_;
    const unsigned* ksb = ksq2  + (size_t)b * M_;

    f32x16 acc[4];
#pragma unroll
    for (int ct = 0; ct < 4; ++ct)
#pragma unroll
      for (int r = 0; r < 16; ++r) acc[ct][r] = 0.f;
    float den = 0.f;

    for (int ms = 0; ms < MSEG / 32; ++ms) {          // 72 iters, no barriers, no LDS
        const int m0 = m_base + ms * 32;

        // K A-frags: contiguous 1KB per load. af[ks] lane offset ((ks*2+h)*32+l31)*8
        const __bf16* ktb = kb + (size_t)(m0 >> 5) * 2048 + ((size_t)h * 32 + l31) * 8;
        bf16x8 af0 = *(const bf16x8*)(ktb);
        bf16x8 af1 = *(const bf16x8*)(ktb + 512);
        bf16x8 af2 = *(const bf16x8*)(ktb + 1024);
        bf16x8 af3 = *(const bf16x8*)(ktb + 1536);
        // ksq rank-2 A-frag: {hi, lo} at k slots {0,1}, h=0 half only
        const unsigned kq2 = ksb[m0 + l31];
        u32x4 a4u = { h ? 0u : kq2, 0u, 0u, 0u };
        const bf16x8 af4 = __builtin_bit_cast(bf16x8, a4u);

        // D = C2Q*ab - C_KSQ*ksq  (exp2-arg), rows m, cols n
        f32x16 d;
#pragma unroll
        for (int r = 0; r < 16; ++r) d[r] = 0.f;
        d = mfma32(af0, qf[0], d);
        d = mfma32(af1, qf[1], d);
        d = mfma32(af2, qf[2], d);
        d = mfma32(af3, qf[3], d);
        d = mfma32(af4, bneg, d);

        // p = exp2(d); pack m-pairs; accumulate denominator
        unsigned wpk[8];
#pragma unroll
        for (int j = 0; j < 8; ++j) {
            const float pa = __builtin_amdgcn_exp2f(d[2*j]);
            const float pb = __builtin_amdgcn_exp2f(d[2*j+1]);
            den += pa + pb;
            wpk[j] = pack_bf16(pa, pb);   // m-pair at 8*(j>>1)+4h+2*(j&1)
        }

        // P B-frags via permlane32_swap (T12): both outputs used
        bf16x8 pb[2];
#pragma unroll
        for (int ks = 0; ks < 2; ++ks) {
            unsigned a0 = wpk[4*ks],     b0 = wpk[4*ks+2];
            unsigned a1 = wpk[4*ks+1],   b1 = wpk[4*ks+3];
            asm volatile("v_permlane32_swap_b32 %0, %1" : "+v"(a0), "+v"(b0));
            asm volatile("v_permlane32_swap_b32 %0, %1" : "+v"(a1), "+v"(b1));
            u32x4 pu = {a0, a1, b0, b1};
            pb[ks] = __builtin_bit_cast(bf16x8, pu);
        }

        // PV: V^T A-frags from vt tiles — lane addr = base + l31*32B + h*16B
        // (contiguous 1KB per load). va(ct,ks) = V[cw+32ct+l31][m0+16ks+8h+i]
        const size_t m16b = (size_t)(m0 >> 4);
#pragma unroll
        for (int ct = 0; ct < 4; ++ct) {
            const __bf16* vp0 = vb + ((m16b)     * CV_ + cw + 32*ct + l31) * 16 + 8*h;
            const __bf16* vp1 = vb + ((m16b + 1) * CV_ + cw + 32*ct + l31) * 16 + 8*h;
            const bf16x8 va0 = *(const bf16x8*)vp0;
            const bf16x8 va1 = *(const bf16x8*)vp1;
            acc[ct] = mfma32(va0, pb[0], acc[ct]);
            acc[ct] = mfma32(va1, pb[1], acc[ct]);
        }
    }

    // denominator: lane holds sum over its 16 m-rows; add other half
    den += __shfl_xor(den, 32);
    if (cs == 0 && lane < 32)
        partD[(size_t)(s * B_ + b) * N_ + n0 + l31] = den;

    // unnormalized partial O in bf16: c = cw + 32ct + (r&3)+8*(r>>2)+4h
    __bf16* po = partO + (((size_t)(s * B_ + b) * CV_ + cw) * N_) + n0 + l31;
#pragma unroll
    for (int ct = 0; ct < 4; ++ct)
#pragma unroll
      for (int r = 0; r < 16; ++r) {
        const int crow = 32*ct + (r & 3) + 8*(r >> 2) + 4*h;
        po[(size_t)crow * N_] = (__bf16)acc[ct][r];
      }
}

// ---------------------------------------------------------------------------
// reduce: mem[b][c][n] = sum_s partO / sum_s partD  -> d_out channels 0..511
// ---------------------------------------------------------------------------
__global__ __launch_bounds__(256) void reduce_kernel(const __bf16* __restrict__ partO,
                                                     const float* __restrict__ partD,
                                                     float* __restrict__ out) {
    const int idx = blockIdx.x * 256 + threadIdx.x;   // B*CV*(N/8) threads
    const int n8 = idx % (N_ / 8);
    const int c  = (idx / (N_ / 8)) % CV_;
    const int b  = idx / ((N_ / 8) * CV_);
    float o[8] = {0,0,0,0,0,0,0,0};
    float dd[8] = {0,0,0,0,0,0,0,0};
#pragma unroll
    for (int s = 0; s < SSPLIT; ++s) {
        const bf16x8 ov = *(const bf16x8*)(partO + (((size_t)(s*B_+b)*CV_ + c) * N_) + n8*8);
        const float4 d0 = *(const float4*)(partD + (size_t)(s*B_+b)*N_ + n8*8);
        const float4 d1 = *(const float4*)(partD + (size_t)(s*B_+b)*N_ + n8*8 + 4);
#pragma unroll
        for (int j = 0; j < 8; ++j) o[j] += (float)ov[j];
        dd[0]+=d0.x; dd[1]+=d0.y; dd[2]+=d0.z; dd[3]+=d0.w;
        dd[4]+=d1.x; dd[5]+=d1.y; dd[6]+=d1.z; dd[7]+=d1.w;
    }
    float* op = out + ((size_t)b * (2*CV_) + c) * N_ + n8*8;
#pragma unroll
    for (int j = 0; j < 8; ++j) op[j] = o[j] / dd[j];
}

// ---------------------------------------------------------------------------
// conv_r: R_j[cc][b][p] = sum_{c in chunk cc} in[c][p] * w[c][j], coalesced
// along p. cc 0..3 -> mem (out rows), 4..7 -> qv, 8 -> mask.
// ---------------------------------------------------------------------------
__global__ __launch_bounds__(256) void conv_r_kernel(const float* __restrict__ outf,
                                                     const float* __restrict__ qv,
                                                     const float* __restrict__ mask,
                                                     const float* __restrict__ cw,
                                                     float* __restrict__ Rp) {
    const int p  = blockIdx.x * 256 + threadIdx.x;   // 0..N-1
    const int cc = blockIdx.y;                        // 0..8
    const int b  = blockIdx.z;
    float r[9] = {0,0,0,0,0,0,0,0,0};
    if (cc < 8) {
        const float* src = (cc < 4) ? outf + ((size_t)b * (2*CV_) + cc * 128) * N_
                                    : qv   + ((size_t)b * CV_ + (cc - 4) * 128) * N_;
        const float* wb = cw + (size_t)cc * 128 * 9;
        for (int c = 0; c < 128; ++c) {
            const float v = src[(size_t)c * N_ + p];
#pragma unroll
            for (int j = 0; j < 9; ++j) r[j] += v * wb[c * 9 + j];
        }
    } else {
        const float v = mask[(size_t)b * N_ + p];
#pragma unroll
        for (int j = 0; j < 9; ++j) r[j] = v * cw[1024 * 9 + j];
    }
#pragma unroll
    for (int j = 0; j < 9; ++j)
        Rp[(((size_t)cc * 9 + j) * B_ + b) * N_ + p] = r[j];
}

// ---------------------------------------------------------------------------
// gate: gate[b][p] = sigmoid( sum_j sum_cc Rp[cc][j][b][neighbor_j(p)] + bias )
// ---------------------------------------------------------------------------
__global__ __launch_bounds__(256) void gate_kernel(const float* __restrict__ Rp,
                                                   const float* __restrict__ cbias,
                                                   float* __restrict__ gate_ws) {
    const int p = blockIdx.x * 256 + threadIdx.x;    // 0..N-1
    const int b = blockIdx.y;
    const int y = p / W_, x = p % W_;
    float sum = cbias[0];
#pragma unroll
    for (int dy = -1; dy <= 1; ++dy) {
        const int yy = y + dy;
        if (yy < 0 || yy >= H_) continue;
#pragma unroll
        for (int dx = -1; dx <= 1; ++dx) {
            const int xx = x + dx;
            if (xx < 0 || xx >= W_) continue;
            const int j = (dy + 1) * 3 + (dx + 1);
            const int q = yy * W_ + xx;
#pragma unroll
            for (int cc = 0; cc < 9; ++cc)
                sum += Rp[(((size_t)cc * 9 + j) * B_ + b) * N_ + q];
        }
    }
    gate_ws[(size_t)b * N_ + p] = 1.f / (1.f + __builtin_amdgcn_exp2f(-sum * 1.44269504f));
}

// ---------------------------------------------------------------------------
// finalize: out[b][ch][n] = (ch<512 ? mem : qv) * gate[b][n]
// ---------------------------------------------------------------------------
__global__ __launch_bounds__(256) void finalize_kernel(const float* __restrict__ qv,
                                                       const float* __restrict__ gate_ws,
                                                       float* __restrict__ out) {
    const int idx = blockIdx.x * 256 + threadIdx.x;
    const int n4 = N_ / 4;
    const int pos4 = idx % n4;
    const int row  = idx / n4;
    const int b = row >> 10, ch = row & 1023;
    const float4 gv = *(const float4*)(gate_ws + (size_t)b * N_ + pos4 * 4);
    float* op = out + (size_t)row * N_ + pos4 * 4;
    float4 v;
    if (ch < CV_) v = *(const float4*)op;
    else          v = *(const float4*)(qv + ((size_t)b * CV_ + (ch - CV_)) * N_ + pos4 * 4);
    v.x *= gv.x; v.y *= gv.y; v.z *= gv.z; v.w *= gv.w;
    *(float4*)op = v;
}

// ===========================================================================
extern "C" void kernel_launch(void* const* d_in, const int* in_sizes, int n_in,
                              void* d_out, int out_size, void* d_ws, size_t ws_size,
                              hipStream_t stream) {
    (void)in_sizes; (void)n_in; (void)out_size; (void)ws_size;
    const float* mk    = (const float*)d_in[0];
    const float* qk    = (const float*)d_in[1];
    const float* mv    = (const float*)d_in[2];
    const float* qv    = (const float*)d_in[3];
    const float* mask  = (const float*)d_in[4];
    const float* cw    = (const float*)d_in[5];
    const float* cbias = (const float*)d_in[6];
    float* outf = (float*)d_out;

    // workspace layout (bytes) — total 80,529,408, byte-identical to round 3/4
    const size_t kbf_b   = (size_t)B_ * M_ * 64 * 2;             //  4,718,592 (ktile; reused as Rp later)
    const size_t vbf_b   = (size_t)B_ * CV_ * M_ * 2;            // 37,748,736 (vt)
    const size_t ksq_b   = (size_t)B_ * M_ * 4;                  //    147,456 (packed u32 hi/lo)
    const size_t partO_b = (size_t)SSPLIT * B_ * CV_ * N_ * 2;   // 37,748,736 (bf16)
    const size_t partD_b = (size_t)SSPLIT * B_ * N_ * 4;         //    147,456

    char* pw = (char*)d_ws;
    __bf16* ktile = (__bf16*)pw;
    float*  Rp    = (float*)pw;            // overlays ktile (dead after flash3); 1.49 MB < 4.7 MB
    pw += kbf_b;
    __bf16* vt    = (__bf16*)pw;           pw += vbf_b;
    unsigned* ksq2 = (unsigned*)pw;        pw += ksq_b;
    __bf16* partO = (__bf16*)pw;           pw += partO_b;
    float*  partD = (float*)pw;            pw += partD_b;
    float*  gate_ws = (float*)pw;

    prep_k<<<dim3(B_ * M_ / 256), 256, 0, stream>>>(mk, ktile, ksq2);
    prep_v<<<dim3((size_t)B_ * (M_ / 16) * CV_ / 256, 1, 1), 256, 0, stream>>>(mv, vt);
    flash3_kernel<<<dim3(1152), 256, 0, stream>>>(ktile, qk, vt, ksq2, partO, partD);
    reduce_kernel<<<dim3(B_ * CV_ * (N_ / 8) / 256), 256, 0, stream>>>(partO, partD, outf);
    conv_r_kernel<<<dim3(N_ / 256, 9, B_), 256, 0, stream>>>(outf, qv, mask, cw, Rp);
    gate_kernel<<<dim3(N_ / 256, B_), 256, 0, stream>>>(Rp, cbias, gate_ws);
    finalize_kernel<<<dim3((B_ * 2 * CV_ * N_ / 4) / 256), 256, 0, stream>>>(qv, gate_ws, outf);
}

// Round 6
// 290.780 us; speedup vs baseline: 11.6527x; 1.2072x over previous
//
#include <hip/hip_runtime.h>

// Problem constants (fixed by setup_inputs)
#define B_  2
#define CK_ 64
#define CV_ 512
#define H_  48
#define W_  48
#define M_  18432   // T*H*W
#define N_  2304    // H*W

#define SSPLIT 8
#define MSEG   (M_ / SSPLIT)   // 2304

typedef __bf16 bf16x8 __attribute__((ext_vector_type(8)));
typedef float  f32x4  __attribute__((ext_vector_type(4)));
typedef float  f32x16 __attribute__((ext_vector_type(16)));
typedef unsigned int u32x4 __attribute__((ext_vector_type(4)));

// logit = (2*ab - |k|^2)/sqrt(64); exp2 domain:
// arg = ab*(2*log2e/8) - ksq*(log2e/8). Q pre-scaled by C2Q at bf16-cast,
// ksq pre-scaled by C_KSQ, stored as bf16 hi+lo pair.
#define C2Q   0.36067376f
#define C_KSQ 0.18033688f

__device__ inline f32x16 mfma32(bf16x8 a, bf16x8 b, f32x16 c) {
    return __builtin_amdgcn_mfma_f32_32x32x16_bf16(a, b, c, 0, 0, 0);
}

__device__ inline unsigned pack_bf16(float lo, float hi) {
    union { __bf16 h; unsigned short u; } a, b;
    a.h = (__bf16)lo; b.h = (__bf16)hi;
    return ((unsigned)b.u << 16) | a.u;
}

// ---------------------------------------------------------------------------
// prep_k: ktile[b][mt][ks][h][l][8] : elem = K[b][m=32mt+l][k=16ks+8h+i]
// (QK A-frag load = contiguous 1KB wave-load). ksq2 = packed bf16 {hi,lo}.
// ---------------------------------------------------------------------------
__global__ __launch_bounds__(256) void prep_k(const float* __restrict__ mk,
                                              __bf16* __restrict__ ktile,
                                              unsigned* __restrict__ ksq2) {
    const int idx = blockIdx.x * 256 + threadIdx.x;   // B*M threads
    const int b = idx / M_, m = idx % M_;
    const float* src = mk + (size_t)b * CK_ * M_ + m;
    const int mt = m >> 5, l = m & 31;
    __bf16* dstb = ktile + (size_t)b * M_ * 64 + (size_t)mt * 2048 + l * 8;
    float s = 0.f;
#pragma unroll
    for (int j = 0; j < 8; ++j) {          // octet j: ks = j>>1, h = j&1
        bf16x8 o;
#pragma unroll
        for (int i = 0; i < 8; ++i) {
            float v = src[(size_t)(8 * j + i) * M_];
            s += v * v;
            o[i] = (__bf16)v;
        }
        *(bf16x8*)(dstb + (size_t)j * 256) = o;
    }
    const float tot = s * C_KSQ;
    const float hi = (float)(__bf16)tot;
    const float lo = tot - hi;
    ksq2[idx] = pack_bf16(hi, lo);
}

// ---------------------------------------------------------------------------
// prep_v: vt[b][m16][c][16] : elem = V[b][c][m=16*m16+i].
// ---------------------------------------------------------------------------
__global__ __launch_bounds__(256) void prep_v(const float* __restrict__ mv,
                                              __bf16* __restrict__ vt) {
    const int idx = blockIdx.x * 256 + threadIdx.x;   // B*1152*CV threads
    const int c   = idx % CV_;
    const int r   = idx / CV_;
    const int m16 = r % (M_ / 16);
    const int b   = r / (M_ / 16);
    const float4* s4 = (const float4*)(mv + ((size_t)b * CV_ + c) * M_ + m16 * 16);
    const float4 a0 = s4[0], a1 = s4[1], a2 = s4[2], a3 = s4[3];
    bf16x8 o0, o1;
    o0[0]=(__bf16)a0.x; o0[1]=(__bf16)a0.y; o0[2]=(__bf16)a0.z; o0[3]=(__bf16)a0.w;
    o0[4]=(__bf16)a1.x; o0[5]=(__bf16)a1.y; o0[6]=(__bf16)a1.z; o0[7]=(__bf16)a1.w;
    o1[0]=(__bf16)a2.x; o1[1]=(__bf16)a2.y; o1[2]=(__bf16)a2.z; o1[3]=(__bf16)a2.w;
    o1[4]=(__bf16)a3.x; o1[5]=(__bf16)a3.y; o1[6]=(__bf16)a3.z; o1[7]=(__bf16)a3.w;
    __bf16* dst = vt + ((size_t)r * CV_ + c) * 16;
    *(bf16x8*)dst = o0;
    *(bf16x8*)(dst + 8) = o1;
}

// ---------------------------------------------------------------------------
// flash4: round-5 flash3b + in-register software pipeline.
//  - per strip: issue V(ms) [8x1KB] FIRST, then K(ms+1)+ksq [5 loads];
//    vmcnt-counted waits keep next-K in flight across the PV.
//  - K double-buffered via 2x-unrolled body (static reg names).
//  - s_setprio around MFMA clusters.
// Math/layout/grid identical to round 5 (verified absmax 0.0156).
// ---------------------------------------------------------------------------

#define LOADK(msx, k0, k1, k2, k3, kq) do {                                   \
    const int _m0 = m_base + (msx) * 32;                                      \
    const __bf16* _ktb = kb + (size_t)(_m0 >> 5) * 2048                       \
                         + ((size_t)h * 32 + l31) * 8;                        \
    k0 = *(const bf16x8*)(_ktb);                                              \
    k1 = *(const bf16x8*)(_ktb + 512);                                        \
    k2 = *(const bf16x8*)(_ktb + 1024);                                       \
    k3 = *(const bf16x8*)(_ktb + 1536);                                       \
    kq = ksb[_m0 + l31];                                                      \
} while (0)

#define LOADV(msx, va) do {                                                   \
    const size_t _m16 = (size_t)((m_base + (msx) * 32) >> 4);                 \
    _Pragma("unroll")                                                         \
    for (int ct = 0; ct < 4; ++ct) {                                          \
        va[ct][0] = *(const bf16x8*)(vb + (_m16 * CV_ + cw + 32*ct + l31) * 16 + 8*h);      \
        va[ct][1] = *(const bf16x8*)(vb + ((_m16 + 1) * CV_ + cw + 32*ct + l31) * 16 + 8*h);\
    }                                                                         \
} while (0)

#define COMPUTE(k0, k1, k2, k3, kq, va) do {                                  \
    u32x4 _a4u = { h ? 0u : (kq), 0u, 0u, 0u };                               \
    const bf16x8 _af4 = __builtin_bit_cast(bf16x8, _a4u);                     \
    f32x16 _d;                                                                \
    _Pragma("unroll") for (int r = 0; r < 16; ++r) _d[r] = 0.f;               \
    __builtin_amdgcn_s_setprio(1);                                            \
    _d = mfma32(k0, qf[0], _d);                                               \
    _d = mfma32(k1, qf[1], _d);                                               \
    _d = mfma32(k2, qf[2], _d);                                               \
    _d = mfma32(k3, qf[3], _d);                                               \
    _d = mfma32(_af4, bneg, _d);                                              \
    __builtin_amdgcn_s_setprio(0);                                            \
    unsigned _wpk[8];                                                         \
    _Pragma("unroll")                                                         \
    for (int j = 0; j < 8; ++j) {                                             \
        const float _pa = __builtin_amdgcn_exp2f(_d[2*j]);                    \
        const float _pc = __builtin_amdgcn_exp2f(_d[2*j+1]);                  \
        den += _pa + _pc;                                                     \
        _wpk[j] = pack_bf16(_pa, _pc);                                        \
    }                                                                         \
    bf16x8 _pb2[2];                                                           \
    _Pragma("unroll")                                                         \
    for (int ks = 0; ks < 2; ++ks) {                                          \
        unsigned _a0 = _wpk[4*ks],   _b0 = _wpk[4*ks+2];                      \
        unsigned _a1 = _wpk[4*ks+1], _b1 = _wpk[4*ks+3];                      \
        asm volatile("v_permlane32_swap_b32 %0, %1" : "+v"(_a0), "+v"(_b0));  \
        asm volatile("v_permlane32_swap_b32 %0, %1" : "+v"(_a1), "+v"(_b1));  \
        u32x4 _pu = {_a0, _a1, _b0, _b1};                                     \
        _pb2[ks] = __builtin_bit_cast(bf16x8, _pu);                           \
    }                                                                         \
    __builtin_amdgcn_s_setprio(1);                                            \
    _Pragma("unroll")                                                         \
    for (int ct = 0; ct < 4; ++ct) {                                          \
        acc[ct] = mfma32(va[ct][0], _pb2[0], acc[ct]);                        \
        acc[ct] = mfma32(va[ct][1], _pb2[1], acc[ct]);                        \
    }                                                                         \
    __builtin_amdgcn_s_setprio(0);                                            \
} while (0)

__global__ __launch_bounds__(256) void flash4_kernel(const __bf16* __restrict__ ktile,
                                                     const float* __restrict__ qk,
                                                     const __bf16* __restrict__ vt,
                                                     const unsigned* __restrict__ ksq2,
                                                     __bf16* __restrict__ partO,
                                                     float* __restrict__ partD) {
    const int tid = threadIdx.x;
    const int w = tid >> 6, lane = tid & 63;
    const int l31 = lane & 31, h = lane >> 5;

    // XCD-chunked decomposition (identical to round 5)
    const int bid = blockIdx.x;            // 0..1151
    const int xcd = bid & 7;
    const int ixc = bid >> 3;              // 0..143
    const int grp = ixc / 18;
    const int blk = ixc % 18;
    const int G   = xcd * 8 + grp;         // 0..63
    const int cs  = G & 3;
    const int sb  = G >> 2;
    const int s   = sb & 7, b = sb >> 3;
    const int nt  = blk * 4 + w;           // 0..71

    const int n0 = nt * 32;
    const int cw = cs * 128;
    const int m_base = s * MSEG;

    // Q' B-frags: col = n0+l31, k = 16ks+8h+i, scaled by C2Q
    const float* qkb = qk + (size_t)b * CK_ * N_;
    bf16x8 qf[4];
#pragma unroll
    for (int ks = 0; ks < 4; ++ks)
#pragma unroll
      for (int i = 0; i < 8; ++i)
        qf[ks][i] = (__bf16)(qkb[(size_t)(16*ks + 8*h + i) * N_ + (n0 + l31)] * C2Q);

    // constant B-frag: -1.0bf16 at k slots {0,1}
    const u32x4 bneg_u = {0xBF80BF80u, 0u, 0u, 0u};
    const bf16x8 bneg = __builtin_bit_cast(bf16x8, bneg_u);

    const __bf16*   kb  = ktile + (size_t)b * M_ * 64;
    const __bf16*   vb  = vt    + (size_t)b * M_ * CV_;
    const unsigned* ksb = ksq2  + (size_t)b * M_;

    f32x16 acc[4];
#pragma unroll
    for (int ct = 0; ct < 4; ++ct)
#pragma unroll
      for (int r = 0; r < 16; ++r) acc[ct][r] = 0.f;
    float den = 0.f;

    // software pipeline: K/ksq prefetched one strip ahead (A/B buffers),
    // V issued at top of each body, consumed at the bottom.
    bf16x8 kA0, kA1, kA2, kA3, kB0, kB1, kB2, kB3;
    unsigned kqA, kqB;
    bf16x8 vaR[4][2];

    LOADK(0, kA0, kA1, kA2, kA3, kqA);

    for (int mss = 0; mss < MSEG / 64; ++mss) {       // 36 double-bodies
        const int msA = 2 * mss;
        // body A: uses K-A, prefetches K-B
        LOADV(msA, vaR);
        LOADK(msA + 1, kB0, kB1, kB2, kB3, kqB);
        COMPUTE(kA0, kA1, kA2, kA3, kqA, vaR);
        // body B: uses K-B, prefetches K-A (clamped on last strip)
        const int msB = msA + 1;
        const int msN = (msB + 1 < MSEG / 32) ? msB + 1 : msB;
        LOADV(msB, vaR);
        LOADK(msN, kA0, kA1, kA2, kA3, kqA);
        COMPUTE(kB0, kB1, kB2, kB3, kqB, vaR);
    }

    // denominator: lane holds sum over its 16 m-rows; add other half
    den += __shfl_xor(den, 32);
    if (cs == 0 && lane < 32)
        partD[(size_t)(s * B_ + b) * N_ + n0 + l31] = den;

    // unnormalized partial O in bf16: c = cw + 32ct + (r&3)+8*(r>>2)+4h
    __bf16* po = partO + (((size_t)(s * B_ + b) * CV_ + cw) * N_) + n0 + l31;
#pragma unroll
    for (int ct = 0; ct < 4; ++ct)
#pragma unroll
      for (int r = 0; r < 16; ++r) {
        const int crow = 32*ct + (r & 3) + 8*(r >> 2) + 4*h;
        po[(size_t)crow * N_] = (__bf16)acc[ct][r];
      }
}

// ---------------------------------------------------------------------------
// reduce: mem[b][c][n] = sum_s partO / sum_s partD  -> d_out channels 0..511
// ---------------------------------------------------------------------------
__global__ __launch_bounds__(256) void reduce_kernel(const __bf16* __restrict__ partO,
                                                     const float* __restrict__ partD,
                                                     float* __restrict__ out) {
    const int idx = blockIdx.x * 256 + threadIdx.x;   // B*CV*(N/8) threads
    const int n8 = idx % (N_ / 8);
    const int c  = (idx / (N_ / 8)) % CV_;
    const int b  = idx / ((N_ / 8) * CV_);
    float o[8] = {0,0,0,0,0,0,0,0};
    float dd[8] = {0,0,0,0,0,0,0,0};
#pragma unroll
    for (int s = 0; s < SSPLIT; ++s) {
        const bf16x8 ov = *(const bf16x8*)(partO + (((size_t)(s*B_+b)*CV_ + c) * N_) + n8*8);
        const float4 d0 = *(const float4*)(partD + (size_t)(s*B_+b)*N_ + n8*8);
        const float4 d1 = *(const float4*)(partD + (size_t)(s*B_+b)*N_ + n8*8 + 4);
#pragma unroll
        for (int j = 0; j < 8; ++j) o[j] += (float)ov[j];
        dd[0]+=d0.x; dd[1]+=d0.y; dd[2]+=d0.z; dd[3]+=d0.w;
        dd[4]+=d1.x; dd[5]+=d1.y; dd[6]+=d1.z; dd[7]+=d1.w;
    }
    float* op = out + ((size_t)b * (2*CV_) + c) * N_ + n8*8;
#pragma unroll
    for (int j = 0; j < 8; ++j) op[j] = o[j] / dd[j];
}

// ---------------------------------------------------------------------------
// conv_r: R_j[cc][b][p] = sum_{c in chunk cc} in[c][p] * w[c][j]
// ---------------------------------------------------------------------------
__global__ __launch_bounds__(256) void conv_r_kernel(const float* __restrict__ outf,
                                                     const float* __restrict__ qv,
                                                     const float* __restrict__ mask,
                                                     const float* __restrict__ cw,
                                                     float* __restrict__ Rp) {
    const int p  = blockIdx.x * 256 + threadIdx.x;   // 0..N-1
    const int cc = blockIdx.y;                        // 0..8
    const int b  = blockIdx.z;
    float r[9] = {0,0,0,0,0,0,0,0,0};
    if (cc < 8) {
        const float* src = (cc < 4) ? outf + ((size_t)b * (2*CV_) + cc * 128) * N_
                                    : qv   + ((size_t)b * CV_ + (cc - 4) * 128) * N_;
        const float* wb = cw + (size_t)cc * 128 * 9;
        for (int c = 0; c < 128; ++c) {
            const float v = src[(size_t)c * N_ + p];
#pragma unroll
            for (int j = 0; j < 9; ++j) r[j] += v * wb[c * 9 + j];
        }
    } else {
        const float v = mask[(size_t)b * N_ + p];
#pragma unroll
        for (int j = 0; j < 9; ++j) r[j] = v * cw[1024 * 9 + j];
    }
#pragma unroll
    for (int j = 0; j < 9; ++j)
        Rp[(((size_t)cc * 9 + j) * B_ + b) * N_ + p] = r[j];
}

// ---------------------------------------------------------------------------
// gate: gate[b][p] = sigmoid( sum_j sum_cc Rp[cc][j][b][neighbor_j(p)] + bias )
// ---------------------------------------------------------------------------
__global__ __launch_bounds__(256) void gate_kernel(const float* __restrict__ Rp,
                                                   const float* __restrict__ cbias,
                                                   float* __restrict__ gate_ws) {
    const int p = blockIdx.x * 256 + threadIdx.x;    // 0..N-1
    const int b = blockIdx.y;
    const int y = p / W_, x = p % W_;
    float sum = cbias[0];
#pragma unroll
    for (int dy = -1; dy <= 1; ++dy) {
        const int yy = y + dy;
        if (yy < 0 || yy >= H_) continue;
#pragma unroll
        for (int dx = -1; dx <= 1; ++dx) {
            const int xx = x + dx;
            if (xx < 0 || xx >= W_) continue;
            const int j = (dy + 1) * 3 + (dx + 1);
            const int q = yy * W_ + xx;
#pragma unroll
            for (int cc = 0; cc < 9; ++cc)
                sum += Rp[(((size_t)cc * 9 + j) * B_ + b) * N_ + q];
        }
    }
    gate_ws[(size_t)b * N_ + p] = 1.f / (1.f + __builtin_amdgcn_exp2f(-sum * 1.44269504f));
}

// ---------------------------------------------------------------------------
// finalize: out[b][ch][n] = (ch<512 ? mem : qv) * gate[b][n]
// ---------------------------------------------------------------------------
__global__ __launch_bounds__(256) void finalize_kernel(const float* __restrict__ qv,
                                                       const float* __restrict__ gate_ws,
                                                       float* __restrict__ out) {
    const int idx = blockIdx.x * 256 + threadIdx.x;
    const int n4 = N_ / 4;
    const int pos4 = idx % n4;
    const int row  = idx / n4;
    const int b = row >> 10, ch = row & 1023;
    const float4 gv = *(const float4*)(gate_ws + (size_t)b * N_ + pos4 * 4);
    float* op = out + (size_t)row * N_ + pos4 * 4;
    float4 v;
    if (ch < CV_) v = *(const float4*)op;
    else          v = *(const float4*)(qv + ((size_t)b * CV_ + (ch - CV_)) * N_ + pos4 * 4);
    v.x *= gv.x; v.y *= gv.y; v.z *= gv.z; v.w *= gv.w;
    *(float4*)op = v;
}

// ===========================================================================
extern "C" void kernel_launch(void* const* d_in, const int* in_sizes, int n_in,
                              void* d_out, int out_size, void* d_ws, size_t ws_size,
                              hipStream_t stream) {
    (void)in_sizes; (void)n_in; (void)out_size; (void)ws_size;
    const float* mk    = (const float*)d_in[0];
    const float* qk    = (const float*)d_in[1];
    const float* mv    = (const float*)d_in[2];
    const float* qv    = (const float*)d_in[3];
    const float* mask  = (const float*)d_in[4];
    const float* cw    = (const float*)d_in[5];
    const float* cbias = (const float*)d_in[6];
    float* outf = (float*)d_out;

    // workspace layout (bytes) — total 80,529,408, byte-identical to rounds 3-5
    const size_t kbf_b   = (size_t)B_ * M_ * 64 * 2;             //  4,718,592 (ktile; reused as Rp)
    const size_t vbf_b   = (size_t)B_ * CV_ * M_ * 2;            // 37,748,736 (vt)
    const size_t ksq_b   = (size_t)B_ * M_ * 4;                  //    147,456 (packed u32 hi/lo)
    const size_t partO_b = (size_t)SSPLIT * B_ * CV_ * N_ * 2;   // 37,748,736 (bf16)
    const size_t partD_b = (size_t)SSPLIT * B_ * N_ * 4;         //    147,456

    char* pw = (char*)d_ws;
    __bf16* ktile = (__bf16*)pw;
    float*  Rp    = (float*)pw;            // overlays ktile (dead after flash4)
    pw += kbf_b;
    __bf16* vt    = (__bf16*)pw;           pw += vbf_b;
    unsigned* ksq2 = (unsigned*)pw;        pw += ksq_b;
    __bf16* partO = (__bf16*)pw;           pw += partO_b;
    float*  partD = (float*)pw;            pw += partD_b;
    float*  gate_ws = (float*)pw;

    prep_k<<<dim3(B_ * M_ / 256), 256, 0, stream>>>(mk, ktile, ksq2);
    prep_v<<<dim3((size_t)B_ * (M_ / 16) * CV_ / 256, 1, 1), 256, 0, stream>>>(mv, vt);
    flash4_kernel<<<dim3(1152), 256, 0, stream>>>(ktile, qk, vt, ksq2, partO, partD);
    reduce_kernel<<<dim3(B_ * CV_ * (N_ / 8) / 256), 256, 0, stream>>>(partO, partD, outf);
    conv_r_kernel<<<dim3(N_ / 256, 9, B_), 256, 0, stream>>>(outf, qv, mask, cw, Rp);
    gate_kernel<<<dim3(N_ / 256, B_), 256, 0, stream>>>(Rp, cbias, gate_ws);
    finalize_kernel<<<dim3((B_ * 2 * CV_ * N_ / 4) / 256), 256, 0, stream>>>(qv, gate_ws, outf);
}

// Round 7
// 277.970 us; speedup vs baseline: 12.1898x; 1.0461x over previous
//
#include <hip/hip_runtime.h>

// Problem constants (fixed by setup_inputs)
#define B_  2
#define CK_ 64
#define CV_ 512
#define H_  48
#define W_  48
#define M_  18432   // T*H*W
#define N_  2304    // H*W

#define SSPLIT 8
#define MSEG   (M_ / SSPLIT)   // 2304
#define VSTRIDE16 (CV_ * 16)   // elems per m16 block in vt = 8192

typedef __bf16 bf16x8 __attribute__((ext_vector_type(8)));
typedef float  f32x4  __attribute__((ext_vector_type(4)));
typedef float  f32x16 __attribute__((ext_vector_type(16)));
typedef unsigned int u32x4 __attribute__((ext_vector_type(4)));

// logit = (2*ab - |k|^2)/sqrt(64); exp2 domain:
// arg = ab*(2*log2e/8) - ksq*(log2e/8). Q pre-scaled by C2Q at bf16-cast,
// ksq pre-scaled by C_KSQ, stored as bf16 hi+lo pair.
#define C2Q   0.36067376f
#define C_KSQ 0.18033688f

__device__ inline f32x16 mfma32(bf16x8 a, bf16x8 b, f32x16 c) {
    return __builtin_amdgcn_mfma_f32_32x32x16_bf16(a, b, c, 0, 0, 0);
}

__device__ inline unsigned pack_bf16(float lo, float hi) {
    union { __bf16 h; unsigned short u; } a, b;
    a.h = (__bf16)lo; b.h = (__bf16)hi;
    return ((unsigned)b.u << 16) | a.u;
}

// ---------------------------------------------------------------------------
// prep_k: ktile[b][mt][ks][h][l][8] : elem = K[b][m=32mt+l][k=16ks+8h+i]
// (QK A-frag load = contiguous 1KB wave-load). ksq2 = packed bf16 {hi,lo}.
// ---------------------------------------------------------------------------
__global__ __launch_bounds__(256) void prep_k(const float* __restrict__ mk,
                                              __bf16* __restrict__ ktile,
                                              unsigned* __restrict__ ksq2) {
    const int idx = blockIdx.x * 256 + threadIdx.x;   // B*M threads
    const int b = idx / M_, m = idx % M_;
    const float* src = mk + (size_t)b * CK_ * M_ + m;
    const int mt = m >> 5, l = m & 31;
    __bf16* dstb = ktile + (size_t)b * M_ * 64 + (size_t)mt * 2048 + l * 8;
    float s = 0.f;
#pragma unroll
    for (int j = 0; j < 8; ++j) {          // octet j: ks = j>>1, h = j&1
        bf16x8 o;
#pragma unroll
        for (int i = 0; i < 8; ++i) {
            float v = src[(size_t)(8 * j + i) * M_];
            s += v * v;
            o[i] = (__bf16)v;
        }
        *(bf16x8*)(dstb + (size_t)j * 256) = o;
    }
    const float tot = s * C_KSQ;
    const float hi = (float)(__bf16)tot;
    const float lo = tot - hi;
    ksq2[idx] = pack_bf16(hi, lo);
}

// ---------------------------------------------------------------------------
// prep_v: vt[b][m16][c][16] : elem = V[b][c][m=16*m16+i].
// ---------------------------------------------------------------------------
__global__ __launch_bounds__(256) void prep_v(const float* __restrict__ mv,
                                              __bf16* __restrict__ vt) {
    const int idx = blockIdx.x * 256 + threadIdx.x;   // B*1152*CV threads
    const int c   = idx % CV_;
    const int r   = idx / CV_;
    const int m16 = r % (M_ / 16);
    const int b   = r / (M_ / 16);
    const float4* s4 = (const float4*)(mv + ((size_t)b * CV_ + c) * M_ + m16 * 16);
    const float4 a0 = s4[0], a1 = s4[1], a2 = s4[2], a3 = s4[3];
    bf16x8 o0, o1;
    o0[0]=(__bf16)a0.x; o0[1]=(__bf16)a0.y; o0[2]=(__bf16)a0.z; o0[3]=(__bf16)a0.w;
    o0[4]=(__bf16)a1.x; o0[5]=(__bf16)a1.y; o0[6]=(__bf16)a1.z; o0[7]=(__bf16)a1.w;
    o1[0]=(__bf16)a2.x; o1[1]=(__bf16)a2.y; o1[2]=(__bf16)a2.z; o1[3]=(__bf16)a2.w;
    o1[4]=(__bf16)a3.x; o1[5]=(__bf16)a3.y; o1[6]=(__bf16)a3.z; o1[7]=(__bf16)a3.w;
    __bf16* dst = vt + ((size_t)r * CV_ + c) * 16;
    *(bf16x8*)dst = o0;
    *(bf16x8*)(dst + 8) = o1;
}

// ---------------------------------------------------------------------------
// flash5: round-6 flash4 + uniform-base addressing diet.
// All loads are (wave-uniform base pointer, advanced by constant stride per
// strip -> SGPR/SALU) + (lane-invariant VGPR offset computed once) + (imm).
// Tail clamp removed via explicit epilogue peel; den split into 4 partials.
// Math/layout/grid identical to rounds 5/6 (verified absmax 0.0156).
// ---------------------------------------------------------------------------

#define LOADK(kp_, kqp_, k0, k1, k2, k3, kq) do {                             \
    k0 = *(const bf16x8*)((kp_) + koff);                                      \
    k1 = *(const bf16x8*)((kp_) + koff + 512);                                \
    k2 = *(const bf16x8*)((kp_) + koff + 1024);                               \
    k3 = *(const bf16x8*)((kp_) + koff + 1536);                               \
    kq = (kqp_)[l31];                                                         \
} while (0)

#define LOADV(vp_, va) do {                                                   \
    _Pragma("unroll")                                                         \
    for (int ct = 0; ct < 4; ++ct) {                                          \
        va[ct][0] = *(const bf16x8*)((vp_) + voff + ct * 512);                \
        va[ct][1] = *(const bf16x8*)((vp_) + VSTRIDE16 + voff + ct * 512);    \
    }                                                                         \
} while (0)

#define COMPUTE(k0, k1, k2, k3, kq, va) do {                                  \
    u32x4 _a4u = { h ? 0u : (kq), 0u, 0u, 0u };                               \
    const bf16x8 _af4 = __builtin_bit_cast(bf16x8, _a4u);                     \
    f32x16 _d;                                                                \
    _Pragma("unroll") for (int r = 0; r < 16; ++r) _d[r] = 0.f;               \
    __builtin_amdgcn_s_setprio(1);                                            \
    _d = mfma32(_af4, bneg, _d);                                              \
    _d = mfma32(k0, qf[0], _d);                                               \
    _d = mfma32(k1, qf[1], _d);                                               \
    _d = mfma32(k2, qf[2], _d);                                               \
    _d = mfma32(k3, qf[3], _d);                                               \
    __builtin_amdgcn_s_setprio(0);                                            \
    unsigned _wpk[8];                                                         \
    _Pragma("unroll")                                                         \
    for (int j = 0; j < 8; ++j) {                                             \
        const float _pa = __builtin_amdgcn_exp2f(_d[2*j]);                    \
        const float _pc = __builtin_amdgcn_exp2f(_d[2*j+1]);                  \
        den[j & 3] += _pa + _pc;                                              \
        _wpk[j] = pack_bf16(_pa, _pc);                                        \
    }                                                                         \
    bf16x8 _pb2[2];                                                           \
    _Pragma("unroll")                                                         \
    for (int ks = 0; ks < 2; ++ks) {                                          \
        unsigned _a0 = _wpk[4*ks],   _b0 = _wpk[4*ks+2];                      \
        unsigned _a1 = _wpk[4*ks+1], _b1 = _wpk[4*ks+3];                      \
        asm volatile("v_permlane32_swap_b32 %0, %1" : "+v"(_a0), "+v"(_b0));  \
        asm volatile("v_permlane32_swap_b32 %0, %1" : "+v"(_a1), "+v"(_b1));  \
        u32x4 _pu = {_a0, _a1, _b0, _b1};                                     \
        _pb2[ks] = __builtin_bit_cast(bf16x8, _pu);                           \
    }                                                                         \
    __builtin_amdgcn_s_setprio(1);                                            \
    _Pragma("unroll")                                                         \
    for (int ct = 0; ct < 4; ++ct) {                                          \
        acc[ct] = mfma32(va[ct][0], _pb2[0], acc[ct]);                        \
        acc[ct] = mfma32(va[ct][1], _pb2[1], acc[ct]);                        \
    }                                                                         \
    __builtin_amdgcn_s_setprio(0);                                            \
} while (0)

__global__ __launch_bounds__(256) void flash5_kernel(const __bf16* __restrict__ ktile,
                                                     const float* __restrict__ qk,
                                                     const __bf16* __restrict__ vt,
                                                     const unsigned* __restrict__ ksq2,
                                                     __bf16* __restrict__ partO,
                                                     float* __restrict__ partD) {
    const int tid = threadIdx.x;
    const int w = tid >> 6, lane = tid & 63;
    const int l31 = lane & 31, h = lane >> 5;

    // XCD-chunked decomposition (identical to rounds 5/6)
    const int bid = blockIdx.x;            // 0..1151
    const int xcd = bid & 7;
    const int ixc = bid >> 3;              // 0..143
    const int grp = ixc / 18;
    const int blk = ixc % 18;
    const int G   = xcd * 8 + grp;         // 0..63
    const int cs  = G & 3;
    const int sb  = G >> 2;
    const int s   = sb & 7, b = sb >> 3;
    const int nt  = blk * 4 + w;           // 0..71

    const int n0 = nt * 32;
    const int cw = cs * 128;
    const int m_base = s * MSEG;

    // lane-invariant load offsets (elements), computed ONCE
    const int koff = (h * 32 + l31) * 8;
    const int voff = (cw + l31) * 16 + 8 * h;

    // Q' B-frags: col = n0+l31, k = 16ks+8h+i, scaled by C2Q
    const float* qkb = qk + (size_t)b * CK_ * N_;
    bf16x8 qf[4];
#pragma unroll
    for (int ks = 0; ks < 4; ++ks)
#pragma unroll
      for (int i = 0; i < 8; ++i)
        qf[ks][i] = (__bf16)(qkb[(size_t)(16*ks + 8*h + i) * N_ + (n0 + l31)] * C2Q);

    // constant B-frag: -1.0bf16 at k slots {0,1}
    const u32x4 bneg_u = {0xBF80BF80u, 0u, 0u, 0u};
    const bf16x8 bneg = __builtin_bit_cast(bf16x8, bneg_u);

    // wave-uniform stream pointers, advanced by constant strides (SALU)
    const __bf16*   kp  = ktile + (size_t)b * M_ * 64 + (size_t)m_base * 64;
    const unsigned* kqp = ksq2  + (size_t)b * M_ + m_base;
    const __bf16*   vp  = vt    + (size_t)b * M_ * CV_ + (size_t)m_base * CV_;

    f32x16 acc[4];
#pragma unroll
    for (int ct = 0; ct < 4; ++ct)
#pragma unroll
      for (int r = 0; r < 16; ++r) acc[ct][r] = 0.f;
    float den[4] = {0.f, 0.f, 0.f, 0.f};

    // software pipeline: K/ksq one strip ahead (A/B static buffers),
    // V issued at top of each body, consumed at the bottom.
    bf16x8 kA0, kA1, kA2, kA3, kB0, kB1, kB2, kB3;
    unsigned kqA, kqB;
    bf16x8 vaR[4][2];

    LOADK(kp, kqp, kA0, kA1, kA2, kA3, kqA);
    kp += 2048; kqp += 32;

    for (int mss = 0; mss < MSEG / 64 - 1; ++mss) {   // 35 double-bodies
        // body A: uses K-A, prefetches K-B
        LOADV(vp, vaR);
        LOADK(kp, kqp, kB0, kB1, kB2, kB3, kqB);
        kp += 2048; kqp += 32;
        COMPUTE(kA0, kA1, kA2, kA3, kqA, vaR);
        vp += 2 * VSTRIDE16;
        // body B: uses K-B, prefetches K-A
        LOADV(vp, vaR);
        LOADK(kp, kqp, kA0, kA1, kA2, kA3, kqA);
        kp += 2048; kqp += 32;
        COMPUTE(kB0, kB1, kB2, kB3, kqB, vaR);
        vp += 2 * VSTRIDE16;
    }
    // epilogue: strips 70 (A) and 71 (B), no over-prefetch
    LOADV(vp, vaR);
    LOADK(kp, kqp, kB0, kB1, kB2, kB3, kqB);
    COMPUTE(kA0, kA1, kA2, kA3, kqA, vaR);
    vp += 2 * VSTRIDE16;
    LOADV(vp, vaR);
    COMPUTE(kB0, kB1, kB2, kB3, kqB, vaR);

    // denominator: lane holds sum over its 16 m-rows; add other half
    float dsum = (den[0] + den[1]) + (den[2] + den[3]);
    dsum += __shfl_xor(dsum, 32);
    if (cs == 0 && lane < 32)
        partD[(size_t)(s * B_ + b) * N_ + n0 + l31] = dsum;

    // unnormalized partial O in bf16: c = cw + 32ct + (r&3)+8*(r>>2)+4h
    __bf16* po = partO + (((size_t)(s * B_ + b) * CV_ + cw) * N_) + n0 + l31;
#pragma unroll
    for (int ct = 0; ct < 4; ++ct)
#pragma unroll
      for (int r = 0; r < 16; ++r) {
        const int crow = 32*ct + (r & 3) + 8*(r >> 2) + 4*h;
        po[(size_t)crow * N_] = (__bf16)acc[ct][r];
      }
}

// ---------------------------------------------------------------------------
// reduce: mem[b][c][n] = sum_s partO / sum_s partD  -> d_out channels 0..511
// ---------------------------------------------------------------------------
__global__ __launch_bounds__(256) void reduce_kernel(const __bf16* __restrict__ partO,
                                                     const float* __restrict__ partD,
                                                     float* __restrict__ out) {
    const int idx = blockIdx.x * 256 + threadIdx.x;   // B*CV*(N/8) threads
    const int n8 = idx % (N_ / 8);
    const int c  = (idx / (N_ / 8)) % CV_;
    const int b  = idx / ((N_ / 8) * CV_);
    float o[8] = {0,0,0,0,0,0,0,0};
    float dd[8] = {0,0,0,0,0,0,0,0};
#pragma unroll
    for (int s = 0; s < SSPLIT; ++s) {
        const bf16x8 ov = *(const bf16x8*)(partO + (((size_t)(s*B_+b)*CV_ + c) * N_) + n8*8);
        const float4 d0 = *(const float4*)(partD + (size_t)(s*B_+b)*N_ + n8*8);
        const float4 d1 = *(const float4*)(partD + (size_t)(s*B_+b)*N_ + n8*8 + 4);
#pragma unroll
        for (int j = 0; j < 8; ++j) o[j] += (float)ov[j];
        dd[0]+=d0.x; dd[1]+=d0.y; dd[2]+=d0.z; dd[3]+=d0.w;
        dd[4]+=d1.x; dd[5]+=d1.y; dd[6]+=d1.z; dd[7]+=d1.w;
    }
    float* op = out + ((size_t)b * (2*CV_) + c) * N_ + n8*8;
#pragma unroll
    for (int j = 0; j < 8; ++j) op[j] = o[j] / dd[j];
}

// ---------------------------------------------------------------------------
// conv_r: R_j[cc][b][p] = sum_{c in chunk cc} in[c][p] * w[c][j]
// ---------------------------------------------------------------------------
__global__ __launch_bounds__(256) void conv_r_kernel(const float* __restrict__ outf,
                                                     const float* __restrict__ qv,
                                                     const float* __restrict__ mask,
                                                     const float* __restrict__ cw,
                                                     float* __restrict__ Rp) {
    const int p  = blockIdx.x * 256 + threadIdx.x;   // 0..N-1
    const int cc = blockIdx.y;                        // 0..8
    const int b  = blockIdx.z;
    float r[9] = {0,0,0,0,0,0,0,0,0};
    if (cc < 8) {
        const float* src = (cc < 4) ? outf + ((size_t)b * (2*CV_) + cc * 128) * N_
                                    : qv   + ((size_t)b * CV_ + (cc - 4) * 128) * N_;
        const float* wb = cw + (size_t)cc * 128 * 9;
        for (int c = 0; c < 128; ++c) {
            const float v = src[(size_t)c * N_ + p];
#pragma unroll
            for (int j = 0; j < 9; ++j) r[j] += v * wb[c * 9 + j];
        }
    } else {
        const float v = mask[(size_t)b * N_ + p];
#pragma unroll
        for (int j = 0; j < 9; ++j) r[j] = v * cw[1024 * 9 + j];
    }
#pragma unroll
    for (int j = 0; j < 9; ++j)
        Rp[(((size_t)cc * 9 + j) * B_ + b) * N_ + p] = r[j];
}

// ---------------------------------------------------------------------------
// gate: gate[b][p] = sigmoid( sum_j sum_cc Rp[cc][j][b][neighbor_j(p)] + bias )
// ---------------------------------------------------------------------------
__global__ __launch_bounds__(256) void gate_kernel(const float* __restrict__ Rp,
                                                   const float* __restrict__ cbias,
                                                   float* __restrict__ gate_ws) {
    const int p = blockIdx.x * 256 + threadIdx.x;    // 0..N-1
    const int b = blockIdx.y;
    const int y = p / W_, x = p % W_;
    float sum = cbias[0];
#pragma unroll
    for (int dy = -1; dy <= 1; ++dy) {
        const int yy = y + dy;
        if (yy < 0 || yy >= H_) continue;
#pragma unroll
        for (int dx = -1; dx <= 1; ++dx) {
            const int xx = x + dx;
            if (xx < 0 || xx >= W_) continue;
            const int j = (dy + 1) * 3 + (dx + 1);
            const int q = yy * W_ + xx;
#pragma unroll
            for (int cc = 0; cc < 9; ++cc)
                sum += Rp[(((size_t)cc * 9 + j) * B_ + b) * N_ + q];
        }
    }
    gate_ws[(size_t)b * N_ + p] = 1.f / (1.f + __builtin_amdgcn_exp2f(-sum * 1.44269504f));
}

// ---------------------------------------------------------------------------
// finalize: out[b][ch][n] = (ch<512 ? mem : qv) * gate[b][n]
// ---------------------------------------------------------------------------
__global__ __launch_bounds__(256) void finalize_kernel(const float* __restrict__ qv,
                                                       const float* __restrict__ gate_ws,
                                                       float* __restrict__ out) {
    const int idx = blockIdx.x * 256 + threadIdx.x;
    const int n4 = N_ / 4;
    const int pos4 = idx % n4;
    const int row  = idx / n4;
    const int b = row >> 10, ch = row & 1023;
    const float4 gv = *(const float4*)(gate_ws + (size_t)b * N_ + pos4 * 4);
    float* op = out + (size_t)row * N_ + pos4 * 4;
    float4 v;
    if (ch < CV_) v = *(const float4*)op;
    else          v = *(const float4*)(qv + ((size_t)b * CV_ + (ch - CV_)) * N_ + pos4 * 4);
    v.x *= gv.x; v.y *= gv.y; v.z *= gv.z; v.w *= gv.w;
    *(float4*)op = v;
}

// ===========================================================================
extern "C" void kernel_launch(void* const* d_in, const int* in_sizes, int n_in,
                              void* d_out, int out_size, void* d_ws, size_t ws_size,
                              hipStream_t stream) {
    (void)in_sizes; (void)n_in; (void)out_size; (void)ws_size;
    const float* mk    = (const float*)d_in[0];
    const float* qk    = (const float*)d_in[1];
    const float* mv    = (const float*)d_in[2];
    const float* qv    = (const float*)d_in[3];
    const float* mask  = (const float*)d_in[4];
    const float* cw    = (const float*)d_in[5];
    const float* cbias = (const float*)d_in[6];
    float* outf = (float*)d_out;

    // workspace layout (bytes) — total 80,529,408, byte-identical to rounds 3-6
    const size_t kbf_b   = (size_t)B_ * M_ * 64 * 2;             //  4,718,592 (ktile; reused as Rp)
    const size_t vbf_b   = (size_t)B_ * CV_ * M_ * 2;            // 37,748,736 (vt)
    const size_t ksq_b   = (size_t)B_ * M_ * 4;                  //    147,456 (packed u32 hi/lo)
    const size_t partO_b = (size_t)SSPLIT * B_ * CV_ * N_ * 2;   // 37,748,736 (bf16)
    const size_t partD_b = (size_t)SSPLIT * B_ * N_ * 4;         //    147,456

    char* pw = (char*)d_ws;
    __bf16* ktile = (__bf16*)pw;
    float*  Rp    = (float*)pw;            // overlays ktile (dead after flash5)
    pw += kbf_b;
    __bf16* vt    = (__bf16*)pw;           pw += vbf_b;
    unsigned* ksq2 = (unsigned*)pw;        pw += ksq_b;
    __bf16* partO = (__bf16*)pw;           pw += partO_b;
    float*  partD = (float*)pw;            pw += partD_b;
    float*  gate_ws = (float*)pw;

    prep_k<<<dim3(B_ * M_ / 256), 256, 0, stream>>>(mk, ktile, ksq2);
    prep_v<<<dim3((size_t)B_ * (M_ / 16) * CV_ / 256, 1, 1), 256, 0, stream>>>(mv, vt);
    flash5_kernel<<<dim3(1152), 256, 0, stream>>>(ktile, qk, vt, ksq2, partO, partD);
    reduce_kernel<<<dim3(B_ * CV_ * (N_ / 8) / 256), 256, 0, stream>>>(partO, partD, outf);
    conv_r_kernel<<<dim3(N_ / 256, 9, B_), 256, 0, stream>>>(outf, qv, mask, cw, Rp);
    gate_kernel<<<dim3(N_ / 256, B_), 256, 0, stream>>>(Rp, cbias, gate_ws);
    finalize_kernel<<<dim3((B_ * 2 * CV_ * N_ / 4) / 256), 256, 0, stream>>>(qv, gate_ws, outf);
}

// Round 8
// 256.890 us; speedup vs baseline: 13.1900x; 1.0821x over previous
//
#include <hip/hip_runtime.h>

// Problem constants (fixed by setup_inputs)
#define B_  2
#define CK_ 64
#define CV_ 512
#define H_  48
#define W_  48
#define M_  18432   // T*H*W
#define N_  2304    // H*W

#define SSPLIT 8
#define MSEG   (M_ / SSPLIT)   // 2304
#define VSTRIDE16 (CV_ * 16)   // elems per m16 block in vt = 8192

typedef __bf16 bf16x8 __attribute__((ext_vector_type(8)));
typedef float  f32x4  __attribute__((ext_vector_type(4)));
typedef float  f32x16 __attribute__((ext_vector_type(16)));
typedef unsigned int u32x4 __attribute__((ext_vector_type(4)));

// logit = (2*ab - |k|^2)/sqrt(64); exp2 domain:
// arg = ab*(2*log2e/8) - ksq*(log2e/8). Q pre-scaled by C2Q at bf16-cast,
// ksq pre-scaled by C_KSQ, stored as bf16 hi+lo pair.
#define C2Q   0.36067376f
#define C_KSQ 0.18033688f

__device__ inline f32x16 mfma32(bf16x8 a, bf16x8 b, f32x16 c) {
    return __builtin_amdgcn_mfma_f32_32x32x16_bf16(a, b, c, 0, 0, 0);
}

__device__ inline unsigned pack_bf16(float lo, float hi) {
    union { __bf16 h; unsigned short u; } a, b;
    a.h = (__bf16)lo; b.h = (__bf16)hi;
    return ((unsigned)b.u << 16) | a.u;
}

// ---------------------------------------------------------------------------
// prep_k: ktile[b][mt][ks][h][l][8] : elem = K[b][m=32mt+l][k=16ks+8h+i]
// (QK A-frag load = contiguous 1KB wave-load). ksq2 = packed bf16 {hi,lo}.
// ---------------------------------------------------------------------------
__global__ __launch_bounds__(256) void prep_k(const float* __restrict__ mk,
                                              __bf16* __restrict__ ktile,
                                              unsigned* __restrict__ ksq2) {
    const int idx = blockIdx.x * 256 + threadIdx.x;   // B*M threads
    const int b = idx / M_, m = idx % M_;
    const float* src = mk + (size_t)b * CK_ * M_ + m;
    const int mt = m >> 5, l = m & 31;
    __bf16* dstb = ktile + (size_t)b * M_ * 64 + (size_t)mt * 2048 + l * 8;
    float s = 0.f;
#pragma unroll
    for (int j = 0; j < 8; ++j) {          // octet j: ks = j>>1, h = j&1
        bf16x8 o;
#pragma unroll
        for (int i = 0; i < 8; ++i) {
            float v = src[(size_t)(8 * j + i) * M_];
            s += v * v;
            o[i] = (__bf16)v;
        }
        *(bf16x8*)(dstb + (size_t)j * 256) = o;
    }
    const float tot = s * C_KSQ;
    const float hi = (float)(__bf16)tot;
    const float lo = tot - hi;
    ksq2[idx] = pack_bf16(hi, lo);
}

// ---------------------------------------------------------------------------
// prep_v: vt[b][m16][c][16] : elem = V[b][c][m=16*m16+i].
// ---------------------------------------------------------------------------
__global__ __launch_bounds__(256) void prep_v(const float* __restrict__ mv,
                                              __bf16* __restrict__ vt) {
    const int idx = blockIdx.x * 256 + threadIdx.x;   // B*1152*CV threads
    const int c   = idx % CV_;
    const int r   = idx / CV_;
    const int m16 = r % (M_ / 16);
    const int b   = r / (M_ / 16);
    const float4* s4 = (const float4*)(mv + ((size_t)b * CV_ + c) * M_ + m16 * 16);
    const float4 a0 = s4[0], a1 = s4[1], a2 = s4[2], a3 = s4[3];
    bf16x8 o0, o1;
    o0[0]=(__bf16)a0.x; o0[1]=(__bf16)a0.y; o0[2]=(__bf16)a0.z; o0[3]=(__bf16)a0.w;
    o0[4]=(__bf16)a1.x; o0[5]=(__bf16)a1.y; o0[6]=(__bf16)a1.z; o0[7]=(__bf16)a1.w;
    o1[0]=(__bf16)a2.x; o1[1]=(__bf16)a2.y; o1[2]=(__bf16)a2.z; o1[3]=(__bf16)a2.w;
    o1[4]=(__bf16)a3.x; o1[5]=(__bf16)a3.y; o1[6]=(__bf16)a3.z; o1[7]=(__bf16)a3.w;
    __bf16* dst = vt + ((size_t)r * CV_ + c) * 16;
    *(bf16x8*)dst = o0;
    *(bf16x8*)(dst + 8) = o1;
}

// ---------------------------------------------------------------------------
// flash6: F=2 channel merge — one wave = 32 queries x 256 channels x one M/8
// segment (cs in {0,1}). Halves the QK/exp/pack redundancy of rounds 3-7
// (was 4x, now 2x). acc = 8 x f32x16 (128 VGPR). Pipeline: K one strip
// ahead; V ks0 issued at body top, V ks1 issued after the exp block (d dead)
// to cap peak VGPR; PV ks0's 8 MFMAs cover va1's flight time.
// Math/layout identical to rounds 5-7 (verified absmax 0.0156).
// ---------------------------------------------------------------------------

#define LOADK(kp_, kqp_, k0, k1, k2, k3, kq) do {                             \
    k0 = *(const bf16x8*)((kp_) + koff);                                      \
    k1 = *(const bf16x8*)((kp_) + koff + 512);                                \
    k2 = *(const bf16x8*)((kp_) + koff + 1024);                               \
    k3 = *(const bf16x8*)((kp_) + koff + 1536);                               \
    kq = (kqp_)[l31];                                                         \
} while (0)

#define LOADV0(vp_) do {                                                      \
    _Pragma("unroll")                                                         \
    for (int ct = 0; ct < 8; ++ct)                                            \
        va0[ct] = *(const bf16x8*)((vp_) + voff + ct * 512);                  \
} while (0)

#define LOADV1(vp_) do {                                                      \
    _Pragma("unroll")                                                         \
    for (int ct = 0; ct < 8; ++ct)                                            \
        va1[ct] = *(const bf16x8*)((vp_) + VSTRIDE16 + voff + ct * 512);      \
} while (0)

// body: uses kc*, prefetches K(next strip) into kn*; V staged va0 (top) and
// va1 (after exp). vp advanced by caller after the body.
#define BODY(kc0, kc1, kc2, kc3, kqc, kn0, kn1, kn2, kn3, kqn, PREFK) do {    \
    LOADV0(vp);                                                               \
    if (PREFK) {                                                              \
        LOADK(kp, kqp, kn0, kn1, kn2, kn3, kqn);                              \
        kp += 2048; kqp += 32;                                                \
    }                                                                         \
    u32x4 _a4u = { h ? 0u : (kqc), 0u, 0u, 0u };                              \
    const bf16x8 _af4 = __builtin_bit_cast(bf16x8, _a4u);                     \
    f32x16 _d;                                                                \
    _Pragma("unroll") for (int r = 0; r < 16; ++r) _d[r] = 0.f;               \
    __builtin_amdgcn_s_setprio(1);                                            \
    _d = mfma32(_af4, bneg, _d);                                              \
    _d = mfma32(kc0, qf[0], _d);                                              \
    _d = mfma32(kc1, qf[1], _d);                                              \
    _d = mfma32(kc2, qf[2], _d);                                              \
    _d = mfma32(kc3, qf[3], _d);                                              \
    __builtin_amdgcn_s_setprio(0);                                            \
    unsigned _wpk[8];                                                         \
    _Pragma("unroll")                                                         \
    for (int j = 0; j < 8; ++j) {                                             \
        const float _pa = __builtin_amdgcn_exp2f(_d[2*j]);                    \
        const float _pc = __builtin_amdgcn_exp2f(_d[2*j+1]);                  \
        den[j & 3] += _pa + _pc;                                              \
        _wpk[j] = pack_bf16(_pa, _pc);                                        \
    }                                                                         \
    bf16x8 _pb0, _pb1;                                                        \
    {                                                                         \
        unsigned _a0 = _wpk[0], _b0 = _wpk[2];                                \
        unsigned _a1 = _wpk[1], _b1 = _wpk[3];                                \
        asm volatile("v_permlane32_swap_b32 %0, %1" : "+v"(_a0), "+v"(_b0));  \
        asm volatile("v_permlane32_swap_b32 %0, %1" : "+v"(_a1), "+v"(_b1));  \
        u32x4 _pu = {_a0, _a1, _b0, _b1};                                     \
        _pb0 = __builtin_bit_cast(bf16x8, _pu);                               \
    }                                                                         \
    {                                                                         \
        unsigned _a0 = _wpk[4], _b0 = _wpk[6];                                \
        unsigned _a1 = _wpk[5], _b1 = _wpk[7];                                \
        asm volatile("v_permlane32_swap_b32 %0, %1" : "+v"(_a0), "+v"(_b0));  \
        asm volatile("v_permlane32_swap_b32 %0, %1" : "+v"(_a1), "+v"(_b1));  \
        u32x4 _pu = {_a0, _a1, _b0, _b1};                                     \
        _pb1 = __builtin_bit_cast(bf16x8, _pu);                               \
    }                                                                         \
    LOADV1(vp);                                                               \
    __builtin_amdgcn_s_setprio(1);                                            \
    _Pragma("unroll")                                                         \
    for (int ct = 0; ct < 8; ++ct)                                            \
        acc[ct] = mfma32(va0[ct], _pb0, acc[ct]);                             \
    _Pragma("unroll")                                                         \
    for (int ct = 0; ct < 8; ++ct)                                            \
        acc[ct] = mfma32(va1[ct], _pb1, acc[ct]);                             \
    __builtin_amdgcn_s_setprio(0);                                            \
} while (0)

__global__ __launch_bounds__(256) void flash6_kernel(const __bf16* __restrict__ ktile,
                                                     const float* __restrict__ qk,
                                                     const __bf16* __restrict__ vt,
                                                     const unsigned* __restrict__ ksq2,
                                                     __bf16* __restrict__ partO,
                                                     float* __restrict__ partD) {
    const int tid = threadIdx.x;
    const int w = tid >> 6, lane = tid & 63;
    const int l31 = lane & 31, h = lane >> 5;

    // XCD-chunked decomposition: 32 groups (cs2,s,b) x 18 blocks; a group's
    // 72 waves share one K/V-segment stream -> one XCD's L2.
    const int bid = blockIdx.x;            // 0..575
    const int xcd = bid & 7;
    const int ixc = bid >> 3;              // 0..71
    const int grp = ixc / 18;              // 0..3
    const int blk = ixc % 18;              // 0..17
    const int G   = xcd * 4 + grp;         // 0..31
    const int cs2 = G & 1;
    const int sb  = G >> 1;                // 0..15
    const int s   = sb & 7, b = sb >> 3;
    const int nt  = blk * 4 + w;           // 0..71

    const int n0 = nt * 32;
    const int cw = cs2 * 256;
    const int m_base = s * MSEG;

    // lane-invariant load offsets (elements), computed ONCE
    const int koff = (h * 32 + l31) * 8;
    const int voff = (cw + l31) * 16 + 8 * h;

    // Q' B-frags: col = n0+l31, k = 16ks+8h+i, scaled by C2Q
    const float* qkb = qk + (size_t)b * CK_ * N_;
    bf16x8 qf[4];
#pragma unroll
    for (int ks = 0; ks < 4; ++ks)
#pragma unroll
      for (int i = 0; i < 8; ++i)
        qf[ks][i] = (__bf16)(qkb[(size_t)(16*ks + 8*h + i) * N_ + (n0 + l31)] * C2Q);

    // constant B-frag: -1.0bf16 at k slots {0,1}
    const u32x4 bneg_u = {0xBF80BF80u, 0u, 0u, 0u};
    const bf16x8 bneg = __builtin_bit_cast(bf16x8, bneg_u);

    // wave-uniform stream pointers, advanced by constant strides (SALU)
    const __bf16*   kp  = ktile + (size_t)b * M_ * 64 + (size_t)m_base * 64;
    const unsigned* kqp = ksq2  + (size_t)b * M_ + m_base;
    const __bf16*   vp  = vt    + (size_t)b * M_ * CV_ + (size_t)m_base * CV_;

    f32x16 acc[8];
#pragma unroll
    for (int ct = 0; ct < 8; ++ct)
#pragma unroll
      for (int r = 0; r < 16; ++r) acc[ct][r] = 0.f;
    float den[4] = {0.f, 0.f, 0.f, 0.f};

    bf16x8 kA0, kA1, kA2, kA3, kB0, kB1, kB2, kB3;
    unsigned kqA, kqB;
    bf16x8 va0[8], va1[8];

    LOADK(kp, kqp, kA0, kA1, kA2, kA3, kqA);
    kp += 2048; kqp += 32;

    for (int mss = 0; mss < MSEG / 64 - 1; ++mss) {   // 35 double-bodies
        BODY(kA0, kA1, kA2, kA3, kqA, kB0, kB1, kB2, kB3, kqB, 1);
        vp += 2 * VSTRIDE16;
        BODY(kB0, kB1, kB2, kB3, kqB, kA0, kA1, kA2, kA3, kqA, 1);
        vp += 2 * VSTRIDE16;
    }
    // epilogue: strips 70 (A, prefetch 71 into B) and 71 (B, no prefetch)
    BODY(kA0, kA1, kA2, kA3, kqA, kB0, kB1, kB2, kB3, kqB, 1);
    vp += 2 * VSTRIDE16;
    BODY(kB0, kB1, kB2, kB3, kqB, kA0, kA1, kA2, kA3, kqA, 0);

    // denominator: lane holds sum over its 16 m-rows; add other half
    float dsum = (den[0] + den[1]) + (den[2] + den[3]);
    dsum += __shfl_xor(dsum, 32);
    if (cs2 == 0 && lane < 32)
        partD[(size_t)(s * B_ + b) * N_ + n0 + l31] = dsum;

    // unnormalized partial O in bf16: c = cw + 32ct + (r&3)+8*(r>>2)+4h
    __bf16* po = partO + (((size_t)(s * B_ + b) * CV_ + cw) * N_) + n0 + l31;
#pragma unroll
    for (int ct = 0; ct < 8; ++ct)
#pragma unroll
      for (int r = 0; r < 16; ++r) {
        const int crow = 32*ct + (r & 3) + 8*(r >> 2) + 4*h;
        po[(size_t)crow * N_] = (__bf16)acc[ct][r];
      }
}

// ---------------------------------------------------------------------------
// reduce: mem[b][c][n] = sum_s partO / sum_s partD  -> d_out channels 0..511
// ---------------------------------------------------------------------------
__global__ __launch_bounds__(256) void reduce_kernel(const __bf16* __restrict__ partO,
                                                     const float* __restrict__ partD,
                                                     float* __restrict__ out) {
    const int idx = blockIdx.x * 256 + threadIdx.x;   // B*CV*(N/8) threads
    const int n8 = idx % (N_ / 8);
    const int c  = (idx / (N_ / 8)) % CV_;
    const int b  = idx / ((N_ / 8) * CV_);
    float o[8] = {0,0,0,0,0,0,0,0};
    float dd[8] = {0,0,0,0,0,0,0,0};
#pragma unroll
    for (int s = 0; s < SSPLIT; ++s) {
        const bf16x8 ov = *(const bf16x8*)(partO + (((size_t)(s*B_+b)*CV_ + c) * N_) + n8*8);
        const float4 d0 = *(const float4*)(partD + (size_t)(s*B_+b)*N_ + n8*8);
        const float4 d1 = *(const float4*)(partD + (size_t)(s*B_+b)*N_ + n8*8 + 4);
#pragma unroll
        for (int j = 0; j < 8; ++j) o[j] += (float)ov[j];
        dd[0]+=d0.x; dd[1]+=d0.y; dd[2]+=d0.z; dd[3]+=d0.w;
        dd[4]+=d1.x; dd[5]+=d1.y; dd[6]+=d1.z; dd[7]+=d1.w;
    }
    float* op = out + ((size_t)b * (2*CV_) + c) * N_ + n8*8;
#pragma unroll
    for (int j = 0; j < 8; ++j) op[j] = o[j] / dd[j];
}

// ---------------------------------------------------------------------------
// conv_r: R_j[cc][b][p] = sum_{c in chunk cc} in[c][p] * w[c][j]
// ---------------------------------------------------------------------------
__global__ __launch_bounds__(256) void conv_r_kernel(const float* __restrict__ outf,
                                                     const float* __restrict__ qv,
                                                     const float* __restrict__ mask,
                                                     const float* __restrict__ cw,
                                                     float* __restrict__ Rp) {
    const int p  = blockIdx.x * 256 + threadIdx.x;   // 0..N-1
    const int cc = blockIdx.y;                        // 0..8
    const int b  = blockIdx.z;
    float r[9] = {0,0,0,0,0,0,0,0,0};
    if (cc < 8) {
        const float* src = (cc < 4) ? outf + ((size_t)b * (2*CV_) + cc * 128) * N_
                                    : qv   + ((size_t)b * CV_ + (cc - 4) * 128) * N_;
        const float* wb = cw + (size_t)cc * 128 * 9;
        for (int c = 0; c < 128; ++c) {
            const float v = src[(size_t)c * N_ + p];
#pragma unroll
            for (int j = 0; j < 9; ++j) r[j] += v * wb[c * 9 + j];
        }
    } else {
        const float v = mask[(size_t)b * N_ + p];
#pragma unroll
        for (int j = 0; j < 9; ++j) r[j] = v * cw[1024 * 9 + j];
    }
#pragma unroll
    for (int j = 0; j < 9; ++j)
        Rp[(((size_t)cc * 9 + j) * B_ + b) * N_ + p] = r[j];
}

// ---------------------------------------------------------------------------
// gate: gate[b][p] = sigmoid( sum_j sum_cc Rp[cc][j][b][neighbor_j(p)] + bias )
// ---------------------------------------------------------------------------
__global__ __launch_bounds__(256) void gate_kernel(const float* __restrict__ Rp,
                                                   const float* __restrict__ cbias,
                                                   float* __restrict__ gate_ws) {
    const int p = blockIdx.x * 256 + threadIdx.x;    // 0..N-1
    const int b = blockIdx.y;
    const int y = p / W_, x = p % W_;
    float sum = cbias[0];
#pragma unroll
    for (int dy = -1; dy <= 1; ++dy) {
        const int yy = y + dy;
        if (yy < 0 || yy >= H_) continue;
#pragma unroll
        for (int dx = -1; dx <= 1; ++dx) {
            const int xx = x + dx;
            if (xx < 0 || xx >= W_) continue;
            const int j = (dy + 1) * 3 + (dx + 1);
            const int q = yy * W_ + xx;
#pragma unroll
            for (int cc = 0; cc < 9; ++cc)
                sum += Rp[(((size_t)cc * 9 + j) * B_ + b) * N_ + q];
        }
    }
    gate_ws[(size_t)b * N_ + p] = 1.f / (1.f + __builtin_amdgcn_exp2f(-sum * 1.44269504f));
}

// ---------------------------------------------------------------------------
// finalize: out[b][ch][n] = (ch<512 ? mem : qv) * gate[b][n]
// ---------------------------------------------------------------------------
__global__ __launch_bounds__(256) void finalize_kernel(const float* __restrict__ qv,
                                                       const float* __restrict__ gate_ws,
                                                       float* __restrict__ out) {
    const int idx = blockIdx.x * 256 + threadIdx.x;
    const int n4 = N_ / 4;
    const int pos4 = idx % n4;
    const int row  = idx / n4;
    const int b = row >> 10, ch = row & 1023;
    const float4 gv = *(const float4*)(gate_ws + (size_t)b * N_ + pos4 * 4);
    float* op = out + (size_t)row * N_ + pos4 * 4;
    float4 v;
    if (ch < CV_) v = *(const float4*)op;
    else          v = *(const float4*)(qv + ((size_t)b * CV_ + (ch - CV_)) * N_ + pos4 * 4);
    v.x *= gv.x; v.y *= gv.y; v.z *= gv.z; v.w *= gv.w;
    *(float4*)op = v;
}

// ===========================================================================
extern "C" void kernel_launch(void* const* d_in, const int* in_sizes, int n_in,
                              void* d_out, int out_size, void* d_ws, size_t ws_size,
                              hipStream_t stream) {
    (void)in_sizes; (void)n_in; (void)out_size; (void)ws_size;
    const float* mk    = (const float*)d_in[0];
    const float* qk    = (const float*)d_in[1];
    const float* mv    = (const float*)d_in[2];
    const float* qv    = (const float*)d_in[3];
    const float* mask  = (const float*)d_in[4];
    const float* cw    = (const float*)d_in[5];
    const float* cbias = (const float*)d_in[6];
    float* outf = (float*)d_out;

    // workspace layout (bytes) — total 80,529,408, byte-identical to rounds 3-7
    const size_t kbf_b   = (size_t)B_ * M_ * 64 * 2;             //  4,718,592 (ktile; reused as Rp)
    const size_t vbf_b   = (size_t)B_ * CV_ * M_ * 2;            // 37,748,736 (vt)
    const size_t ksq_b   = (size_t)B_ * M_ * 4;                  //    147,456 (packed u32 hi/lo)
    const size_t partO_b = (size_t)SSPLIT * B_ * CV_ * N_ * 2;   // 37,748,736 (bf16)
    const size_t partD_b = (size_t)SSPLIT * B_ * N_ * 4;         //    147,456

    char* pw = (char*)d_ws;
    __bf16* ktile = (__bf16*)pw;
    float*  Rp    = (float*)pw;            // overlays ktile (dead after flash6)
    pw += kbf_b;
    __bf16* vt    = (__bf16*)pw;           pw += vbf_b;
    unsigned* ksq2 = (unsigned*)pw;        pw += ksq_b;
    __bf16* partO = (__bf16*)pw;           pw += partO_b;
    float*  partD = (float*)pw;            pw += partD_b;
    float*  gate_ws = (float*)pw;

    prep_k<<<dim3(B_ * M_ / 256), 256, 0, stream>>>(mk, ktile, ksq2);
    prep_v<<<dim3((size_t)B_ * (M_ / 16) * CV_ / 256, 1, 1), 256, 0, stream>>>(mv, vt);
    flash6_kernel<<<dim3(576), 256, 0, stream>>>(ktile, qk, vt, ksq2, partO, partD);
    reduce_kernel<<<dim3(B_ * CV_ * (N_ / 8) / 256), 256, 0, stream>>>(partO, partD, outf);
    conv_r_kernel<<<dim3(N_ / 256, 9, B_), 256, 0, stream>>>(outf, qv, mask, cw, Rp);
    gate_kernel<<<dim3(N_ / 256, B_), 256, 0, stream>>>(Rp, cbias, gate_ws);
    finalize_kernel<<<dim3((B_ * 2 * CV_ * N_ / 4) / 256), 256, 0, stream>>>(qv, gate_ws, outf);
}